// Round 15
// baseline (597.153 us; speedup 1.0000x reference)
//
#include <hip/hip_runtime.h>
#include <hip/hip_bf16.h>
#include <cmath>

#define N0 50000
#define NEDGE 800000
#define NEG_HUGE -3.402823466e38f
#define STRIDE 128   // max degree slots per node (Poisson(16): P(deg>=128) ~ 0)
#define HBINS 6250   // histogram bins per range (8 ranges x 6250 = N0)
#define HSLICE 8     // edge slices; blockIdx = slice*8 + range -> range r on XCD r

typedef int i32x4 __attribute__((ext_vector_type(4)));
typedef __attribute__((ext_vector_type(8))) short short8v;   // 8 bf16 = 4 VGPR
typedef __attribute__((ext_vector_type(4))) float f32x4;

// ---------- helpers ----------
__device__ inline float b2f(unsigned short u) { return __uint_as_float(((unsigned)u) << 16); }

__device__ inline unsigned short f2b(float f) {
    __hip_bfloat16 h = __float2bfloat16(f);
    return *(unsigned short*)&h;
}

__device__ inline unsigned fkey(float f) {
    unsigned b = __float_as_uint(f);
    if (b == 0x80000000u) b = 0u;  // canonicalize -0 -> +0
    return (b & 0x80000000u) ? ~b : (b | 0x80000000u);
}

__device__ inline void atomicMaxF(float* a, float v) {
    if (v >= 0.f) atomicMax((int*)a, __float_as_int(v));
    else          atomicMin((unsigned int*)a, __float_as_uint(v));
}

// ---------- init: zero counters / accumulators / bins / maxbuf / edge counters ----------
__global__ void k_init(float* finalv, float* f1raw, int* deg_out, int* fill,
                       int* binsA, int* binsB, float* maxbuf, int* ctrl) {
    int i = blockIdx.x * blockDim.x + threadIdx.x;   // 256 x 256 = 65536
    if (i < 256) { finalv[i] = 0.f; f1raw[i] = 0.f; }
    if (i < 384) maxbuf[i] = NEG_HUGE;
    if (i < N0) { deg_out[i] = 0; fill[i] = 0; }
    if (i < 65536) { binsA[i] = 0; binsB[i] = 0; }
    if (i < 2) ctrl[8 + i] = 0;
}

// ---------- L0 node histogram: LDS-privatized, ZERO global atomics ----------
// 64 blocks = 8 slices x 8 node-ranges; blockIdx = slice*8 + r so all blocks
// of range r land on XCD r (round-robin) -> XCD-local partial writes.
// R12 verified the mechanism: removing 800K device atomics cut k_build 87->62;
// R14 (full src histogram) -> 49us. This pass runs on src AND dst.
__global__ __launch_bounds__(1024) void k_hist(const int* __restrict__ earr,
                                               unsigned* __restrict__ part) {
    __shared__ unsigned hist[HBINS];
    int b = blockIdx.x;
    int r = b & 7;           // node range: [r*HBINS, (r+1)*HBINS)
    int slice = b >> 3;      // 0..7
    for (int i = threadIdx.x; i < HBINS; i += 1024) hist[i] = 0;
    __syncthreads();
    int lo = r * HBINS;
    int base = slice * (NEDGE / HSLICE);   // 100000-edge slice
    for (int e = threadIdx.x * 4; e < NEDGE / HSLICE; e += 4096) {
        i32x4 a = __builtin_nontemporal_load((const i32x4*)(earr + base + e));
        int ss[4] = {a.x, a.y, a.z, a.w};
#pragma unroll
        for (int q = 0; q < 4; ++q) {
            unsigned loc = (unsigned)(ss[q] - lo);
            if (loc < (unsigned)HBINS) atomicAdd(&hist[loc], 1u);
        }
    }
    __syncthreads();
    for (int i = threadIdx.x; i < HBINS; i += 1024)
        part[(size_t)slice * N0 + lo + i] = hist[i];
}

// ---------- totals + exclusive slice offsets ----------
// deg_out[v] = sum of src partials; dp_d converted in-place to exclusive
// offsets per (slice, node); fill[v] = total in-degree.
__global__ void k_dsum(const unsigned* __restrict__ dp_s, unsigned* dp_d,
                       int* deg_out, int* fill) {
    int v = blockIdx.x * 256 + threadIdx.x;
    if (v >= N0) return;
    unsigned s = 0;
#pragma unroll
    for (int q = 0; q < HSLICE; ++q) s += dp_s[(size_t)q * N0 + v];
    deg_out[v] = (int)s;
    unsigned off = 0;
#pragma unroll
    for (int q = 0; q < HSLICE; ++q) {
        unsigned t = dp_d[(size_t)q * N0 + v];
        dp_d[(size_t)q * N0 + v] = off;
        off += t;
    }
    fill[v] = (int)off;
}

// ---------- L0 CSR fill via LDS cursors: ZERO global atomics ----------
// Same 8x8 geometry as k_hist. Block loads its range's slice offsets into an
// LDS cursor, scans its edge slice, assigns slots with on-CU ds_add.
// All csr writes for range r issue from XCD r -> full-line writebacks.
__global__ __launch_bounds__(1024) void k_fill(
        const int* __restrict__ esrc, const int* __restrict__ edst,
        const unsigned* __restrict__ foff, int* csr_src) {
    __shared__ unsigned cur[HBINS];
    int b = blockIdx.x;
    int r = b & 7;
    int slice = b >> 3;
    int lo = r * HBINS;
    for (int i = threadIdx.x; i < HBINS; i += 1024)
        cur[i] = foff[(size_t)slice * N0 + lo + i];
    __syncthreads();
    int base = slice * (NEDGE / HSLICE);
    for (int e = threadIdx.x * 4; e < NEDGE / HSLICE; e += 4096) {
        i32x4 sv = __builtin_nontemporal_load((const i32x4*)(esrc + base + e));
        i32x4 dv = __builtin_nontemporal_load((const i32x4*)(edst + base + e));
        int ss[4] = {sv.x, sv.y, sv.z, sv.w};
        int dd[4] = {dv.x, dv.y, dv.z, dv.w};
#pragma unroll
        for (int q = 0; q < 4; ++q) {
            unsigned loc = (unsigned)(dd[q] - lo);
            if (loc < (unsigned)HBINS) {
                unsigned pos = atomicAdd(&cur[loc], 1u);
                if (pos < STRIDE) csr_src[(size_t)dd[q] * STRIDE + pos] = ss[q];
            }
        }
    }
}

// ---------- fused remap + compact + build (levels 1,2) ----------
__global__ __launch_bounds__(256) void k_rmbuild(
        const int* __restrict__ esrc, const int* __restrict__ edst,
        const int2* __restrict__ ein, int use_pair,
        const int* __restrict__ ctrl, int slot,
        const int* __restrict__ newid,
        int2* __restrict__ eout, int* __restrict__ outcnt,
        int* deg_out, int* fill, int* csr_src) {
    __shared__ int wbase[4];
    __shared__ int blkbase;
    int E = (slot < 0) ? NEDGE : ctrl[slot];
    if (blockIdx.x * 256 >= E) return;   // block-uniform early exit
    int i = blockIdx.x * 256 + threadIdx.x;
    int lane = threadIdx.x & 63, w = threadIdx.x >> 6;
    int ns = -1, nd = -1;
    if (i < E) {
        int s, d;
        if (use_pair) { int2 pr = ein[i]; s = pr.x; d = pr.y; }
        else { s = esrc[i]; d = edst[i]; }
        ns = newid[s]; nd = newid[d];
    }
    bool keep = (ns >= 0) && (nd >= 0);
    unsigned long long m = __ballot(keep);
    int rank = __popcll(m & ((1ull << lane) - 1ull));
    if (lane == 0) wbase[w] = __popcll(m);
    __syncthreads();
    if (threadIdx.x == 0)
        blkbase = atomicAdd(outcnt, wbase[0] + wbase[1] + wbase[2] + wbase[3]);
    __syncthreads();
    int base = blkbase;
    for (int q = 0; q < w; ++q) base += wbase[q];
    if (keep) {
        eout[base + rank] = make_int2(ns, nd);
        atomicAdd(&deg_out[ns], 1);
        int pos = atomicAdd(&fill[nd], 1);
        if (pos < STRIDE) csr_src[(size_t)nd * STRIDE + pos] = ns;
    }
}

// ---------- MFMA GEMM: h_pre(bf16) = esc[r] * (X @ W)[r] ----------
__global__ __launch_bounds__(256) void k_gemm(
        const float* __restrict__ feat, const float* __restrict__ xprev,
        const int* __restrict__ oldid, const float* __restrict__ garr,
        const int* __restrict__ deg_out,
        const float* __restrict__ W, unsigned short* __restrict__ hpre,
        int n, int nprev, int mode) {
    __shared__ short Wt[128][136];   // [col][k]
    __shared__ short Xt[64][136];    // [row][k]
    __shared__ int ridx_s[64];
    __shared__ float esc_s[64];
    int tid = threadIdx.x;
    int r0 = blockIdx.x * 64;
    if (tid < 64) {
        int gr = r0 + tid;
        int ridx = 0; float esc = 0.f;
        if (gr < n) {
            if (mode == 0) {
                ridx = gr;
                esc = rsqrtf(fmaxf((float)deg_out[gr], 1.f));
            } else {
                int orow = oldid[gr];
                if ((unsigned)orow < (unsigned)nprev) {
                    ridx = orow;
                    esc = rsqrtf(fmaxf((float)deg_out[gr], 1.f)) * garr[gr];
                }
            }
        }
        ridx_s[tid] = ridx;
        esc_s[tid] = esc;
    }
    __syncthreads();   // ridx_s visible to X stagers
    {   // stage W -> Wt[col][k] bf16
        int col = tid & 127;
        int kh = tid >> 7;
#pragma unroll
        for (int c8 = 0; c8 < 8; ++c8) {
            int kb = kh * 64 + c8 * 8;
            unsigned short v[8];
#pragma unroll
            for (int j = 0; j < 8; ++j)
                v[j] = f2b(W[(size_t)(kb + j) * 128 + col]);
            *(uint4*)&Wt[col][kb] = *(uint4*)v;
        }
    }
    {   // stage X tile -> Xt[row][k] bf16: 4 threads/row, 32 floats each
        const float* xsrc = (mode == 0) ? feat : xprev;
        int rr = tid >> 2;
        int kx = (tid & 3) * 32;
        const float4* xp = (const float4*)(xsrc + (size_t)ridx_s[rr] * 128 + kx);
#pragma unroll
        for (int c4 = 0; c4 < 8; ++c4) {
            float4 v = xp[c4];
            unsigned short u[4];
            u[0] = f2b(v.x); u[1] = f2b(v.y); u[2] = f2b(v.z); u[3] = f2b(v.w);
            *(uint2*)&Xt[rr][kx + c4 * 4] = *(uint2*)u;
        }
    }
    __syncthreads();

    int lane = tid & 63, w = tid >> 6;
    int row16 = lane & 15;
    int ko = (lane >> 4) * 8;
    f32x4 acc[8];
#pragma unroll
    for (int t = 0; t < 8; ++t) acc[t] = (f32x4){0.f, 0.f, 0.f, 0.f};
#pragma unroll
    for (int kc = 0; kc < 4; ++kc) {
        int kbase = kc * 32 + ko;
        short8v a = *(short8v*)&Xt[w * 16 + row16][kbase];
#pragma unroll
        for (int t = 0; t < 8; ++t) {
            short8v b = *(short8v*)&Wt[t * 16 + row16][kbase];
            acc[t] = __builtin_amdgcn_mfma_f32_16x16x32_bf16(a, b, acc[t], 0, 0, 0);
        }
    }
    int rq = (lane >> 4) * 4;
    float esc[4];
#pragma unroll
    for (int r = 0; r < 4; ++r) esc[r] = esc_s[w * 16 + rq + r];
#pragma unroll
    for (int r = 0; r < 4; ++r) {
        int gr = r0 + w * 16 + rq + r;
        if (gr < n) {
            unsigned short* op = hpre + (size_t)gr * 128;
#pragma unroll
            for (int t = 0; t < 8; ++t)
                op[t * 16 + (lane & 15)] = f2b(acc[t][r] * esc[r]);
        }
    }
}

// ---------- edge aggregation: 2 rows/wave (32 lanes x ushort4 per row) ----------
__global__ __launch_bounds__(256) void k_agg_conv(
        const unsigned short* __restrict__ hpre, const int* __restrict__ fill,
        const int* __restrict__ deg_out,
        const int* __restrict__ csr_src,
        const float* __restrict__ cb, const float* __restrict__ sW,
        float* __restrict__ hpost, float* __restrict__ hs, int n) {
    int wid = threadIdx.x >> 6;
    int lane = threadIdx.x & 63;
    int d = blockIdx.x * 4 + wid;
    if (d >= n) return;
    int degin = fill[d];
    int cnt = min(degin, STRIDE);
    const int* bp = csr_src + (size_t)d * STRIDE;
    int half = lane >> 5;        // 0: even rows, 1: odd rows
    int l32 = lane & 31;
    float a0 = 0.f, a1 = 0.f, a2 = 0.f, a3 = 0.f;   // cols c = l32*4 + q
    int j = 0;
    for (; j + 8 <= cnt; j += 8) {
        int s0 = bp[j + half];
        int s1 = bp[j + 2 + half];
        int s2 = bp[j + 4 + half];
        int s3 = bp[j + 6 + half];
        ushort4 u0 = ((const ushort4*)(hpre + (size_t)s0 * 128))[l32];
        ushort4 u1 = ((const ushort4*)(hpre + (size_t)s1 * 128))[l32];
        ushort4 u2 = ((const ushort4*)(hpre + (size_t)s2 * 128))[l32];
        ushort4 u3 = ((const ushort4*)(hpre + (size_t)s3 * 128))[l32];
        a0 += (b2f(u0.x) + b2f(u1.x)) + (b2f(u2.x) + b2f(u3.x));
        a1 += (b2f(u0.y) + b2f(u1.y)) + (b2f(u2.y) + b2f(u3.y));
        a2 += (b2f(u0.z) + b2f(u1.z)) + (b2f(u2.z) + b2f(u3.z));
        a3 += (b2f(u0.w) + b2f(u1.w)) + (b2f(u2.w) + b2f(u3.w));
    }
    for (; j < cnt; j += 2) {
        int jj = j + half;
        if (jj < cnt) {
            int s0 = bp[jj];
            ushort4 u0 = ((const ushort4*)(hpre + (size_t)s0 * 128))[l32];
            a0 += b2f(u0.x); a1 += b2f(u0.y); a2 += b2f(u0.z); a3 += b2f(u0.w);
        }
    }
    // combine even/odd halves (both halves end with identical totals)
    a0 += __shfl_xor(a0, 32);
    a1 += __shfl_xor(a1, 32);
    a2 += __shfl_xor(a2, 32);
    a3 += __shfl_xor(a3, 32);
    float nd2 = rsqrtf(fmaxf((float)degin, 1.f));
    int c0 = l32 * 4;
    float h0 = fmaxf(fmaf(a0, nd2, cb[c0]), 0.f);
    float h1 = fmaxf(fmaf(a1, nd2, cb[c0 + 1]), 0.f);
    float h2 = fmaxf(fmaf(a2, nd2, cb[c0 + 2]), 0.f);
    float h3 = fmaxf(fmaf(a3, nd2, cb[c0 + 3]), 0.f);
    if (half == 0)
        ((float4*)(hpost + (size_t)d * 128))[l32] = make_float4(h0, h1, h2, h3);
    float v = h0 * sW[c0] + h1 * sW[c0 + 1] + h2 * sW[c0 + 2] + h3 * sW[c0 + 3];
#pragma unroll
    for (int off = 16; off; off >>= 1) v += __shfl_down(v, off);
    if (lane == 0) hs[d] = v * rsqrtf(fmaxf((float)deg_out[d], 1.f));  // pre-scale
}

// ---------- score + radix histogram pass 1 (top 16 bits) fused; unroll-8 ----------
__global__ void k_score_hist(const float* __restrict__ hs, const int* __restrict__ fill,
                             const int* __restrict__ csr_src,
                             const float* __restrict__ sb, float* score,
                             int* binsA, int n) {
    int d = blockIdx.x * blockDim.x + threadIdx.x;
    if (d >= n) return;
    int degin = fill[d];
    int cnt = min(degin, STRIDE);
    const int* bp = csr_src + (size_t)d * STRIDE;
    float sum = 0.f;
    int j = 0;
    for (; j + 8 <= cnt; j += 8) {
        int4 s0 = *(const int4*)(bp + j);
        int4 s1 = *(const int4*)(bp + j + 4);
        sum += ((hs[s0.x] + hs[s0.y]) + (hs[s0.z] + hs[s0.w])) +
               ((hs[s1.x] + hs[s1.y]) + (hs[s1.z] + hs[s1.w]));
    }
    for (; j + 4 <= cnt; j += 4) {
        int4 ss = *(const int4*)(bp + j);
        sum += (hs[ss.x] + hs[ss.y]) + (hs[ss.z] + hs[ss.w]);
    }
    for (; j < cnt; ++j) sum += hs[bp[j]];
    float sc = rsqrtf(fmaxf((float)degin, 1.f)) * sum + sb[0];
    score[d] = sc;
    atomicAdd(&binsA[fkey(sc) >> 16], 1);
}

// ---------- radix histogram pass 2 (low 16 bits of matching prefix) ----------
__global__ void k_rhist2(const float* __restrict__ score, const int* __restrict__ ctrl,
                         int n, int* binsB) {
    unsigned p16 = (unsigned)ctrl[3];
    for (int i = blockIdx.x * 256 + threadIdx.x; i < n; i += gridDim.x * 256) {
        unsigned u = fkey(score[i]);
        if ((u >> 16) == p16) atomicAdd(&binsB[u & 0xFFFFu], 1);
    }
}

// ---------- radix pick with integrated chunk sums: 1 block 1024 thr ----------
__global__ void k_rpick(int stage, int k0, int* ctrl, const int* __restrict__ bins) {
    __shared__ int gs[64];
    __shared__ int arr[1024];
    __shared__ int wsum[16];
    __shared__ int sChunk, sKrem;
    int t = threadIdx.x;  // 1024
    {   // chunk sums: 16 threads per chunk of 1024 bins, 16 int4 each
        int c = t >> 4, sub = t & 15;
        const int4* p4 = (const int4*)(bins + (size_t)c * 1024);
        int s = 0;
#pragma unroll
        for (int q = 0; q < 16; ++q) {
            int4 v = p4[q * 16 + sub];
            s += v.x + v.y + v.z + v.w;
        }
#pragma unroll
        for (int off = 8; off; off >>= 1) s += __shfl_down(s, off, 16);
        if (sub == 0) gs[c] = s;
    }
    __syncthreads();
    if (t == 0) {
        int kneed = (stage == 0) ? k0 : ctrl[4];
        int cum = 0, c = 63;
        for (; c >= 1; --c) { int v = gs[c]; if (cum + v >= kneed) break; cum += v; }
        sChunk = c; sKrem = kneed - cum;
    }
    __syncthreads();
    int c = sChunk;
    int v = bins[(size_t)c * 1024 + t];
    arr[t] = v;
    int lane = t & 63, w = t >> 6;
    int s = v;
#pragma unroll
    for (int off = 32; off; off >>= 1) s += __shfl_down(s, off);
    if (lane == 0) wsum[w] = s;
    __syncthreads();
    if (t == 0) {
        int kneed = sKrem;
        int cum = 0, w2 = 15;
        for (; w2 >= 1; --w2) { int vv = wsum[w2]; if (cum + vv >= kneed) break; cum += vv; }
        int j = 63;
        for (; j >= 1; --j) { int vv = arr[w2 * 64 + j]; if (cum + vv >= kneed) break; cum += vv; }
        int bin = c * 1024 + w2 * 64 + j;
        if (stage == 0) { ctrl[3] = bin; ctrl[4] = kneed - cum; }
        else {
            ctrl[0] = (int)((((unsigned)ctrl[3]) << 16) | (unsigned)bin);
            ctrl[2] = kneed - cum;
        }
    }
}

// ---------- fused count+emit+readout ----------
__global__ __launch_bounds__(1024) void k_cemit2(
        const float* __restrict__ score, const int* __restrict__ ctrl,
        int n, int knext, int* newid, int* oldid, float* garr,
        int* deg_out, int* fill, int* binsA, int* binsB,
        const float* __restrict__ hpost, float* finalv, float* maxbuf, float invk) {
    __shared__ int wG[16], wE[16];
    __shared__ int redCG[16], redCE[16];
    __shared__ int selIdx[1024];
    __shared__ float selG[1024];
    __shared__ int selCnt;
    __shared__ float redS[1024], redM[1024];
    int b = blockIdx.x, tid = threadIdx.x;
    int lane = tid & 63, wv = tid >> 6;
    unsigned T = (unsigned)ctrl[0];
    int needEq = ctrl[2];

    if (knext > 0) {
        int gt = b * 1024 + tid, nt = gridDim.x * 1024;
        for (int z = gt; z < 65536; z += nt) { binsA[z] = 0; binsB[z] = 0; }
        for (int z = gt; z < knext; z += nt) { deg_out[z] = 0; fill[z] = 0; }
    }

    // prefix recount over [0, b*1024)
    int cg_ = 0, ce_ = 0;
    int end = b << 10;
    for (int i = tid; i < end; i += 1024) {
        unsigned u = fkey(score[i]);
        cg_ += (u > T);
        ce_ += (u == T);
    }
#pragma unroll
    for (int off = 32; off; off >>= 1) {
        cg_ += __shfl_down(cg_, off);
        ce_ += __shfl_down(ce_, off);
    }
    if (lane == 0) { redCG[wv] = cg_; redCE[wv] = ce_; }
    if (tid == 0) selCnt = 0;

    int i = (b << 10) + tid;
    bool inb = (i < n);
    float sc = inb ? score[i] : 0.f;
    unsigned u = inb ? fkey(sc) : 0u;
    bool isG = inb && (u > T);
    bool isE = inb && (u == T);
    unsigned long long mG = __ballot(isG);
    unsigned long long mE = __ballot(isE);
    if (lane == 0) { wG[wv] = __popcll(mG); wE[wv] = __popcll(mE); }
    __syncthreads();

    int sGoff = 0, sEoff = 0;
#pragma unroll
    for (int w = 0; w < 16; ++w) { sGoff += redCG[w]; sEoff += redCE[w]; }
    int gW = 0, eW = 0;
    for (int w = 0; w < wv; ++w) { gW += wG[w]; eW += wE[w]; }
    unsigned long long below = (1ull << lane) - 1ull;
    int Gb = sGoff + gW + __popcll(mG & below);
    int Eb = sEoff + eW + __popcll(mE & below);
    if (inb) {
        bool sel = isG || (isE && (Eb < needEq));
        if (sel) {
            int j = Gb + min(Eb, needEq);
            newid[i] = j;
            oldid[j] = i;
            float g = tanhf(sc);
            garr[j] = g;
            int p = atomicAdd(&selCnt, 1);
            selIdx[p] = i;
            selG[p] = g;
        } else {
            newid[i] = -1;
        }
    }
    __syncthreads();

    int m = selCnt;
    int grp = tid >> 7, c = tid & 127;
    float sum = 0.f, mx = NEG_HUGE;
    for (int r = grp; r < m; r += 8) {
        float v = hpost[(size_t)selIdx[r] * 128 + c] * selG[r];
        sum += v;
        mx = fmaxf(mx, v);
    }
    redS[tid] = sum;
    redM[tid] = mx;
    __syncthreads();
    if (tid < 128) {
        float s2 = 0.f, m2 = NEG_HUGE;
#pragma unroll
        for (int g2 = 0; g2 < 8; ++g2) {
            s2 += redS[g2 * 128 + tid];
            m2 = fmaxf(m2, redM[g2 * 128 + tid]);
        }
        atomicAdd(&finalv[tid], s2 * invk);
        atomicMaxF(&maxbuf[tid], m2);
    }
}

// ---------- MLP: 3 parallel kernels (multi-block — single-block fusion was a
// 65us serialization: 1 CU streaming 2.4MB of weights; measured R12) ----------
__global__ void k_mlp1(const float* __restrict__ finalv, const float* __restrict__ maxbuf,
                       const float* __restrict__ seq, const float* __restrict__ W1,
                       float* f1raw) {
    int o = threadIdx.x;             // 256
    int j0 = blockIdx.x * 128;       // 10 blocks
    float acc = 0.f;
    for (int jj = 0; jj < 128; ++jj) {
        int j = j0 + jj;
        float fv;
        if (j < 128) fv = finalv[j];
        else if (j < 256) fv = maxbuf[j - 128] + maxbuf[j] + maxbuf[j + 128];
        else fv = seq[j - 256];
        acc = fmaf(fv, W1[(size_t)j * 256 + o], acc);
    }
    atomicAdd(&f1raw[o], acc);
}

__global__ void k_mlp2(const float* __restrict__ f1raw, const float* __restrict__ b1,
                       const float* __restrict__ W2, const float* __restrict__ bb2,
                       float* f2v) {
    __shared__ float f1s[256];
    int t = threadIdx.x;  // 128
    f1s[t] = fmaxf(f1raw[t] + b1[t], 0.f);
    f1s[t + 128] = fmaxf(f1raw[t + 128] + b1[t + 128], 0.f);
    __syncthreads();
    float acc = 0.f;
    for (int j = 0; j < 256; ++j)
        acc = fmaf(f1s[j], W2[(size_t)j * 128 + t], acc);
    f2v[t] = fmaxf(acc + bb2[t], 0.f);
}

__global__ void k_mlp3(const float* __restrict__ f2v, const float* __restrict__ W3,
                       const float* __restrict__ b3, float* out) {
    __shared__ float f2s[128];
    int t = threadIdx.x;  // 128
    f2s[t] = f2v[t];
    __syncthreads();
    int col = blockIdx.x * 128 + t;  // 16 blocks
    float acc = 0.f;
    for (int j = 0; j < 128; ++j)
        acc = fmaf(f2s[j], W3[(size_t)j * 2048 + col], acc);
    out[col] = acc + b3[col];
}

// ---------- host ----------
extern "C" void kernel_launch(void* const* d_in, const int* in_sizes, int n_in,
                              void* d_out, int out_size, void* d_ws, size_t ws_size,
                              hipStream_t stream) {
    (void)in_sizes; (void)n_in; (void)out_size; (void)ws_size;
    const float* feat = (const float*)d_in[0];
    const float* seq  = (const float*)d_in[1];
    const int* src = (const int*)d_in[2];
    const int* dst = (const int*)d_in[3];
    // d_in[4], d_in[5]: label_src/label_dst — dead code in reference, unused.
    const float *cW[3], *cb[3], *sW[3], *sb[3];
    for (int b = 0; b < 3; ++b) {
        cW[b] = (const float*)d_in[6 + 4 * b];
        cb[b] = (const float*)d_in[7 + 4 * b];
        sW[b] = (const float*)d_in[8 + 4 * b];
        sb[b] = (const float*)d_in[9 + 4 * b];
    }
    const float* lin1W = (const float*)d_in[18];
    const float* lin1b = (const float*)d_in[19];
    const float* lin2W = (const float*)d_in[20];
    const float* lin2b = (const float*)d_in[21];
    const float* lin3W = (const float*)d_in[22];
    const float* lin3b = (const float*)d_in[23];
    float* out = (float*)d_out;

    char* p = (char*)d_ws;
    size_t off = 0;
    auto alloc = [&](size_t bytes) -> void* {
        void* r = p + off;
        off = (off + bytes + 255) & ~(size_t)255;
        return r;
    };
    unsigned short* hpre = (unsigned short*)alloc((size_t)N0 * 128 * 2);  // bf16
    float* hpost  = (float*)alloc((size_t)N0 * 128 * 4);
    float* hs     = (float*)alloc((size_t)N0 * 4);
    float* score  = (float*)alloc((size_t)N0 * 4);
    int* deg_out  = (int*)alloc((size_t)N0 * 4);
    int* fill     = (int*)alloc((size_t)N0 * 4);
    unsigned* dp_s = (unsigned*)alloc((size_t)HSLICE * N0 * 4);  // src partials
    unsigned* dp_d = (unsigned*)alloc((size_t)HSLICE * N0 * 4);  // dst partials/offsets
    int2* epair1  = (int2*)alloc((size_t)NEDGE * 8);   // compacted level-1 edges
    int* csr_src  = (int*)alloc((size_t)N0 * STRIDE * 4);
    int* newid    = (int*)alloc((size_t)N0 * 4);
    int* oldid    = (int*)alloc((size_t)25000 * 4);
    float* garr   = (float*)alloc((size_t)25000 * 4);
    float* maxbuf = (float*)alloc(3 * 128 * 4);
    float* finalv = (float*)alloc(256 * 4);
    float* f1raw  = (float*)alloc(256 * 4);
    float* f2v    = (float*)alloc(128 * 4);
    int* ctrl     = (int*)alloc(64 * 4);
    int* binsA    = (int*)alloc(65536 * 4);
    int* binsB    = (int*)alloc(65536 * 4);
    // epair2 lives only between L2-rmbuild and consumption; hpre is dead then.
    int2* epair2  = (int2*)hpre;

    const int nb[3] = {50000, 25000, 12500};
    const int kb[3] = {25000, 12500, 6250};

    k_init<<<256, 256, 0, stream>>>(finalv, f1raw, deg_out, fill, binsA, binsB,
                                    maxbuf, ctrl);

    for (int b = 0; b < 3; ++b) {
        int n = nb[b], k = kb[b];
        int B = (n + 1023) / 1024;
        if (b == 0) {
            k_hist<<<64, 1024, 0, stream>>>(src, dp_s);
            k_hist<<<64, 1024, 0, stream>>>(dst, dp_d);
            k_dsum<<<(N0 + 255) / 256, 256, 0, stream>>>(dp_s, dp_d, deg_out, fill);
            k_fill<<<64, 1024, 0, stream>>>(src, dst, dp_d, csr_src);
        } else if (b == 1) {
            k_rmbuild<<<(NEDGE + 255) / 256, 256, 0, stream>>>(
                src, dst, (const int2*)0, 0, ctrl, -1, newid, epair1, ctrl + 8,
                deg_out, fill, csr_src);
        } else {
            k_rmbuild<<<(NEDGE + 255) / 256, 256, 0, stream>>>(
                (const int*)0, (const int*)0, epair1, 1, ctrl, 8, newid, epair2, ctrl + 9,
                deg_out, fill, csr_src);
        }
        k_gemm<<<(n + 63) / 64, 256, 0, stream>>>(feat, hpost, oldid, garr, deg_out, cW[b],
                                                  hpre, n, (b > 0) ? nb[b - 1] : 1,
                                                  (b == 0) ? 0 : 1);
        k_agg_conv<<<(n + 3) / 4, 256, 0, stream>>>(hpre, fill, deg_out, csr_src, cb[b],
                                                    sW[b], hpost, hs, n);
        k_score_hist<<<(n + 255) / 256, 256, 0, stream>>>(hs, fill, csr_src, sb[b],
                                                          score, binsA, n);
        k_rpick<<<1, 1024, 0, stream>>>(0, k, ctrl, binsA);
        k_rhist2<<<128, 256, 0, stream>>>(score, ctrl, n, binsB);
        k_rpick<<<1, 1024, 0, stream>>>(1, k, ctrl, binsB);
        k_cemit2<<<B, 1024, 0, stream>>>(score, ctrl, n, (b < 2) ? kb[b] : 0,
                                         newid, oldid, garr, deg_out, fill, binsA, binsB,
                                         hpost, finalv, maxbuf + b * 128,
                                         1.0f / (float)k);
    }

    k_mlp1<<<10, 256, 0, stream>>>(finalv, maxbuf, seq, lin1W, f1raw);
    k_mlp2<<<1, 128, 0, stream>>>(f1raw, lin1b, lin2W, lin2b, f2v);
    k_mlp3<<<16, 128, 0, stream>>>(f2v, lin3W, lin3b, out);
}

// Round 16
// 549.766 us; speedup vs baseline: 1.0862x; 1.0862x over previous
//
#include <hip/hip_runtime.h>
#include <hip/hip_bf16.h>
#include <cmath>

#define N0 50000
#define NEDGE 800000
#define NEG_HUGE -3.402823466e38f
#define STRIDE 128   // max degree slots per node (Poisson(16): P(deg>=128) ~ 0)
#define HBINS 6250   // histogram bins per range (8 ranges x 6250 = N0)
#define HSLICE 32    // edge slices; blockIdx = slice*8 + range -> range r on XCD r

typedef int i32x4 __attribute__((ext_vector_type(4)));
typedef __attribute__((ext_vector_type(8))) short short8v;   // 8 bf16 = 4 VGPR
typedef __attribute__((ext_vector_type(4))) float f32x4;

// ---------- helpers ----------
__device__ inline float b2f(unsigned short u) { return __uint_as_float(((unsigned)u) << 16); }

__device__ inline unsigned short f2b(float f) {
    __hip_bfloat16 h = __float2bfloat16(f);
    return *(unsigned short*)&h;
}

__device__ inline unsigned fkey(float f) {
    unsigned b = __float_as_uint(f);
    if (b == 0x80000000u) b = 0u;  // canonicalize -0 -> +0
    return (b & 0x80000000u) ? ~b : (b | 0x80000000u);
}

__device__ inline void atomicMaxF(float* a, float v) {
    if (v >= 0.f) atomicMax((int*)a, __float_as_int(v));
    else          atomicMin((unsigned int*)a, __float_as_uint(v));
}

// ---------- init: zero counters / accumulators / bins / maxbuf / edge counters ----------
__global__ void k_init(float* finalv, float* f1raw, int* deg_out, int* fill,
                       int* binsA, int* binsB, float* maxbuf, int* ctrl) {
    int i = blockIdx.x * blockDim.x + threadIdx.x;   // 256 x 256 = 65536
    if (i < 256) { finalv[i] = 0.f; f1raw[i] = 0.f; }
    if (i < 384) maxbuf[i] = NEG_HUGE;
    if (i < N0) { deg_out[i] = 0; fill[i] = 0; }
    if (i < 65536) { binsA[i] = 0; binsB[i] = 0; }
    if (i < 2) ctrl[8 + i] = 0;
}

// ---------- L0 dual histogram (src + dst): LDS-privatized, ZERO global atomics ----------
// 256 blocks = 32 slices x 8 node-ranges; blockIdx = slice*8 + r so all blocks
// of range r land on XCD r (round-robin) -> XCD-local partial writes.
// R15's 64-block version was parallelism-starved (Occupancy 8.9%, 64/256 CUs);
// 256 blocks fills the chip. One edge scan counts BOTH src and dst (50KB LDS).
__global__ __launch_bounds__(1024) void k_hist2(
        const int* __restrict__ esrc, const int* __restrict__ edst,
        unsigned* __restrict__ dp_s, unsigned* __restrict__ dp_d) {
    __shared__ unsigned hist_s[HBINS];
    __shared__ unsigned hist_d[HBINS];
    int b = blockIdx.x;
    int r = b & 7;           // node range: [r*HBINS, (r+1)*HBINS)
    int slice = b >> 3;      // 0..31
    for (int i = threadIdx.x; i < HBINS; i += 1024) { hist_s[i] = 0; hist_d[i] = 0; }
    __syncthreads();
    int lo = r * HBINS;
    int base = slice * (NEDGE / HSLICE);   // 25000-edge slice
    for (int e = threadIdx.x * 4; e < NEDGE / HSLICE; e += 4096) {
        i32x4 sv = __builtin_nontemporal_load((const i32x4*)(esrc + base + e));
        i32x4 dv = __builtin_nontemporal_load((const i32x4*)(edst + base + e));
        int ss[4] = {sv.x, sv.y, sv.z, sv.w};
        int dd[4] = {dv.x, dv.y, dv.z, dv.w};
#pragma unroll
        for (int q = 0; q < 4; ++q) {
            unsigned ls = (unsigned)(ss[q] - lo);
            if (ls < (unsigned)HBINS) atomicAdd(&hist_s[ls], 1u);
            unsigned ld = (unsigned)(dd[q] - lo);
            if (ld < (unsigned)HBINS) atomicAdd(&hist_d[ld], 1u);
        }
    }
    __syncthreads();
    for (int i = threadIdx.x; i < HBINS; i += 1024) {
        dp_s[(size_t)slice * N0 + lo + i] = hist_s[i];
        dp_d[(size_t)slice * N0 + lo + i] = hist_d[i];
    }
}

// ---------- totals + exclusive slice offsets ----------
__global__ void k_dsum(const unsigned* __restrict__ dp_s, unsigned* dp_d,
                       int* deg_out, int* fill) {
    int v = blockIdx.x * 256 + threadIdx.x;
    if (v >= N0) return;
    unsigned s = 0;
#pragma unroll
    for (int q = 0; q < HSLICE; ++q) s += dp_s[(size_t)q * N0 + v];
    deg_out[v] = (int)s;
    unsigned off = 0;
#pragma unroll
    for (int q = 0; q < HSLICE; ++q) {
        unsigned t = dp_d[(size_t)q * N0 + v];
        dp_d[(size_t)q * N0 + v] = off;
        off += t;
    }
    fill[v] = (int)off;
}

// ---------- L0 CSR fill via LDS cursors: ZERO global atomics ----------
// Same 32x8 geometry. Block loads its range's slice offsets into an LDS
// cursor, scans its 25K-edge slice, assigns slots with on-CU ds_add.
// All csr writes for range r issue from XCD r -> full-line writebacks
// (R15 verified: WRITE_SIZE 48.5 -> 3.8 MB).
__global__ __launch_bounds__(1024) void k_fill(
        const int* __restrict__ esrc, const int* __restrict__ edst,
        const unsigned* __restrict__ foff, int* csr_src) {
    __shared__ unsigned cur[HBINS];
    int b = blockIdx.x;
    int r = b & 7;
    int slice = b >> 3;
    int lo = r * HBINS;
    for (int i = threadIdx.x; i < HBINS; i += 1024)
        cur[i] = foff[(size_t)slice * N0 + lo + i];
    __syncthreads();
    int base = slice * (NEDGE / HSLICE);
    for (int e = threadIdx.x * 4; e < NEDGE / HSLICE; e += 4096) {
        i32x4 sv = __builtin_nontemporal_load((const i32x4*)(esrc + base + e));
        i32x4 dv = __builtin_nontemporal_load((const i32x4*)(edst + base + e));
        int ss[4] = {sv.x, sv.y, sv.z, sv.w};
        int dd[4] = {dv.x, dv.y, dv.z, dv.w};
#pragma unroll
        for (int q = 0; q < 4; ++q) {
            unsigned loc = (unsigned)(dd[q] - lo);
            if (loc < (unsigned)HBINS) {
                unsigned pos = atomicAdd(&cur[loc], 1u);
                if (pos < STRIDE) csr_src[(size_t)dd[q] * STRIDE + pos] = ss[q];
            }
        }
    }
}

// ---------- fused remap + compact + build (levels 1,2) ----------
__global__ __launch_bounds__(256) void k_rmbuild(
        const int* __restrict__ esrc, const int* __restrict__ edst,
        const int2* __restrict__ ein, int use_pair,
        const int* __restrict__ ctrl, int slot,
        const int* __restrict__ newid,
        int2* __restrict__ eout, int* __restrict__ outcnt,
        int* deg_out, int* fill, int* csr_src) {
    __shared__ int wbase[4];
    __shared__ int blkbase;
    int E = (slot < 0) ? NEDGE : ctrl[slot];
    if (blockIdx.x * 256 >= E) return;   // block-uniform early exit
    int i = blockIdx.x * 256 + threadIdx.x;
    int lane = threadIdx.x & 63, w = threadIdx.x >> 6;
    int ns = -1, nd = -1;
    if (i < E) {
        int s, d;
        if (use_pair) { int2 pr = ein[i]; s = pr.x; d = pr.y; }
        else { s = esrc[i]; d = edst[i]; }
        ns = newid[s]; nd = newid[d];
    }
    bool keep = (ns >= 0) && (nd >= 0);
    unsigned long long m = __ballot(keep);
    int rank = __popcll(m & ((1ull << lane) - 1ull));
    if (lane == 0) wbase[w] = __popcll(m);
    __syncthreads();
    if (threadIdx.x == 0)
        blkbase = atomicAdd(outcnt, wbase[0] + wbase[1] + wbase[2] + wbase[3]);
    __syncthreads();
    int base = blkbase;
    for (int q = 0; q < w; ++q) base += wbase[q];
    if (keep) {
        eout[base + rank] = make_int2(ns, nd);
        atomicAdd(&deg_out[ns], 1);
        int pos = atomicAdd(&fill[nd], 1);
        if (pos < STRIDE) csr_src[(size_t)nd * STRIDE + pos] = ns;
    }
}

// ---------- MFMA GEMM: h_pre(bf16) = esc[r] * (X @ W)[r] ----------
__global__ __launch_bounds__(256) void k_gemm(
        const float* __restrict__ feat, const float* __restrict__ xprev,
        const int* __restrict__ oldid, const float* __restrict__ garr,
        const int* __restrict__ deg_out,
        const float* __restrict__ W, unsigned short* __restrict__ hpre,
        int n, int nprev, int mode) {
    __shared__ short Wt[128][136];   // [col][k]
    __shared__ short Xt[64][136];    // [row][k]
    __shared__ int ridx_s[64];
    __shared__ float esc_s[64];
    int tid = threadIdx.x;
    int r0 = blockIdx.x * 64;
    if (tid < 64) {
        int gr = r0 + tid;
        int ridx = 0; float esc = 0.f;
        if (gr < n) {
            if (mode == 0) {
                ridx = gr;
                esc = rsqrtf(fmaxf((float)deg_out[gr], 1.f));
            } else {
                int orow = oldid[gr];
                if ((unsigned)orow < (unsigned)nprev) {
                    ridx = orow;
                    esc = rsqrtf(fmaxf((float)deg_out[gr], 1.f)) * garr[gr];
                }
            }
        }
        ridx_s[tid] = ridx;
        esc_s[tid] = esc;
    }
    __syncthreads();   // ridx_s visible to X stagers
    {   // stage W -> Wt[col][k] bf16
        int col = tid & 127;
        int kh = tid >> 7;
#pragma unroll
        for (int c8 = 0; c8 < 8; ++c8) {
            int kb = kh * 64 + c8 * 8;
            unsigned short v[8];
#pragma unroll
            for (int j = 0; j < 8; ++j)
                v[j] = f2b(W[(size_t)(kb + j) * 128 + col]);
            *(uint4*)&Wt[col][kb] = *(uint4*)v;
        }
    }
    {   // stage X tile -> Xt[row][k] bf16: 4 threads/row, 32 floats each
        const float* xsrc = (mode == 0) ? feat : xprev;
        int rr = tid >> 2;
        int kx = (tid & 3) * 32;
        const float4* xp = (const float4*)(xsrc + (size_t)ridx_s[rr] * 128 + kx);
#pragma unroll
        for (int c4 = 0; c4 < 8; ++c4) {
            float4 v = xp[c4];
            unsigned short u[4];
            u[0] = f2b(v.x); u[1] = f2b(v.y); u[2] = f2b(v.z); u[3] = f2b(v.w);
            *(uint2*)&Xt[rr][kx + c4 * 4] = *(uint2*)u;
        }
    }
    __syncthreads();

    int lane = tid & 63, w = tid >> 6;
    int row16 = lane & 15;
    int ko = (lane >> 4) * 8;
    f32x4 acc[8];
#pragma unroll
    for (int t = 0; t < 8; ++t) acc[t] = (f32x4){0.f, 0.f, 0.f, 0.f};
#pragma unroll
    for (int kc = 0; kc < 4; ++kc) {
        int kbase = kc * 32 + ko;
        short8v a = *(short8v*)&Xt[w * 16 + row16][kbase];
#pragma unroll
        for (int t = 0; t < 8; ++t) {
            short8v b = *(short8v*)&Wt[t * 16 + row16][kbase];
            acc[t] = __builtin_amdgcn_mfma_f32_16x16x32_bf16(a, b, acc[t], 0, 0, 0);
        }
    }
    int rq = (lane >> 4) * 4;
    float esc[4];
#pragma unroll
    for (int r = 0; r < 4; ++r) esc[r] = esc_s[w * 16 + rq + r];
#pragma unroll
    for (int r = 0; r < 4; ++r) {
        int gr = r0 + w * 16 + rq + r;
        if (gr < n) {
            unsigned short* op = hpre + (size_t)gr * 128;
#pragma unroll
            for (int t = 0; t < 8; ++t)
                op[t * 16 + (lane & 15)] = f2b(acc[t][r] * esc[r]);
        }
    }
}

// ---------- edge aggregation: 2 rows/wave (32 lanes x ushort4 per row) ----------
__global__ __launch_bounds__(256) void k_agg_conv(
        const unsigned short* __restrict__ hpre, const int* __restrict__ fill,
        const int* __restrict__ deg_out,
        const int* __restrict__ csr_src,
        const float* __restrict__ cb, const float* __restrict__ sW,
        float* __restrict__ hpost, float* __restrict__ hs, int n) {
    int wid = threadIdx.x >> 6;
    int lane = threadIdx.x & 63;
    int d = blockIdx.x * 4 + wid;
    if (d >= n) return;
    int degin = fill[d];
    int cnt = min(degin, STRIDE);
    const int* bp = csr_src + (size_t)d * STRIDE;
    int half = lane >> 5;        // 0: even rows, 1: odd rows
    int l32 = lane & 31;
    float a0 = 0.f, a1 = 0.f, a2 = 0.f, a3 = 0.f;   // cols c = l32*4 + q
    int j = 0;
    for (; j + 8 <= cnt; j += 8) {
        int s0 = bp[j + half];
        int s1 = bp[j + 2 + half];
        int s2 = bp[j + 4 + half];
        int s3 = bp[j + 6 + half];
        ushort4 u0 = ((const ushort4*)(hpre + (size_t)s0 * 128))[l32];
        ushort4 u1 = ((const ushort4*)(hpre + (size_t)s1 * 128))[l32];
        ushort4 u2 = ((const ushort4*)(hpre + (size_t)s2 * 128))[l32];
        ushort4 u3 = ((const ushort4*)(hpre + (size_t)s3 * 128))[l32];
        a0 += (b2f(u0.x) + b2f(u1.x)) + (b2f(u2.x) + b2f(u3.x));
        a1 += (b2f(u0.y) + b2f(u1.y)) + (b2f(u2.y) + b2f(u3.y));
        a2 += (b2f(u0.z) + b2f(u1.z)) + (b2f(u2.z) + b2f(u3.z));
        a3 += (b2f(u0.w) + b2f(u1.w)) + (b2f(u2.w) + b2f(u3.w));
    }
    for (; j < cnt; j += 2) {
        int jj = j + half;
        if (jj < cnt) {
            int s0 = bp[jj];
            ushort4 u0 = ((const ushort4*)(hpre + (size_t)s0 * 128))[l32];
            a0 += b2f(u0.x); a1 += b2f(u0.y); a2 += b2f(u0.z); a3 += b2f(u0.w);
        }
    }
    // combine even/odd halves (both halves end with identical totals)
    a0 += __shfl_xor(a0, 32);
    a1 += __shfl_xor(a1, 32);
    a2 += __shfl_xor(a2, 32);
    a3 += __shfl_xor(a3, 32);
    float nd2 = rsqrtf(fmaxf((float)degin, 1.f));
    int c0 = l32 * 4;
    float h0 = fmaxf(fmaf(a0, nd2, cb[c0]), 0.f);
    float h1 = fmaxf(fmaf(a1, nd2, cb[c0 + 1]), 0.f);
    float h2 = fmaxf(fmaf(a2, nd2, cb[c0 + 2]), 0.f);
    float h3 = fmaxf(fmaf(a3, nd2, cb[c0 + 3]), 0.f);
    if (half == 0)
        ((float4*)(hpost + (size_t)d * 128))[l32] = make_float4(h0, h1, h2, h3);
    float v = h0 * sW[c0] + h1 * sW[c0 + 1] + h2 * sW[c0 + 2] + h3 * sW[c0 + 3];
#pragma unroll
    for (int off = 16; off; off >>= 1) v += __shfl_down(v, off);
    if (lane == 0) hs[d] = v * rsqrtf(fmaxf((float)deg_out[d], 1.f));  // pre-scale
}

// ---------- score + radix histogram pass 1 (top 16 bits) fused; unroll-8 ----------
__global__ void k_score_hist(const float* __restrict__ hs, const int* __restrict__ fill,
                             const int* __restrict__ csr_src,
                             const float* __restrict__ sb, float* score,
                             int* binsA, int n) {
    int d = blockIdx.x * blockDim.x + threadIdx.x;
    if (d >= n) return;
    int degin = fill[d];
    int cnt = min(degin, STRIDE);
    const int* bp = csr_src + (size_t)d * STRIDE;
    float sum = 0.f;
    int j = 0;
    for (; j + 8 <= cnt; j += 8) {
        int4 s0 = *(const int4*)(bp + j);
        int4 s1 = *(const int4*)(bp + j + 4);
        sum += ((hs[s0.x] + hs[s0.y]) + (hs[s0.z] + hs[s0.w])) +
               ((hs[s1.x] + hs[s1.y]) + (hs[s1.z] + hs[s1.w]));
    }
    for (; j + 4 <= cnt; j += 4) {
        int4 ss = *(const int4*)(bp + j);
        sum += (hs[ss.x] + hs[ss.y]) + (hs[ss.z] + hs[ss.w]);
    }
    for (; j < cnt; ++j) sum += hs[bp[j]];
    float sc = rsqrtf(fmaxf((float)degin, 1.f)) * sum + sb[0];
    score[d] = sc;
    atomicAdd(&binsA[fkey(sc) >> 16], 1);
}

// ---------- radix histogram pass 2 (low 16 bits of matching prefix) ----------
__global__ void k_rhist2(const float* __restrict__ score, const int* __restrict__ ctrl,
                         int n, int* binsB) {
    unsigned p16 = (unsigned)ctrl[3];
    for (int i = blockIdx.x * 256 + threadIdx.x; i < n; i += gridDim.x * 256) {
        unsigned u = fkey(score[i]);
        if ((u >> 16) == p16) atomicAdd(&binsB[u & 0xFFFFu], 1);
    }
}

// ---------- radix pick with integrated chunk sums: 1 block 1024 thr ----------
__global__ void k_rpick(int stage, int k0, int* ctrl, const int* __restrict__ bins) {
    __shared__ int gs[64];
    __shared__ int arr[1024];
    __shared__ int wsum[16];
    __shared__ int sChunk, sKrem;
    int t = threadIdx.x;  // 1024
    {   // chunk sums: 16 threads per chunk of 1024 bins, 16 int4 each
        int c = t >> 4, sub = t & 15;
        const int4* p4 = (const int4*)(bins + (size_t)c * 1024);
        int s = 0;
#pragma unroll
        for (int q = 0; q < 16; ++q) {
            int4 v = p4[q * 16 + sub];
            s += v.x + v.y + v.z + v.w;
        }
#pragma unroll
        for (int off = 8; off; off >>= 1) s += __shfl_down(s, off, 16);
        if (sub == 0) gs[c] = s;
    }
    __syncthreads();
    if (t == 0) {
        int kneed = (stage == 0) ? k0 : ctrl[4];
        int cum = 0, c = 63;
        for (; c >= 1; --c) { int v = gs[c]; if (cum + v >= kneed) break; cum += v; }
        sChunk = c; sKrem = kneed - cum;
    }
    __syncthreads();
    int c = sChunk;
    int v = bins[(size_t)c * 1024 + t];
    arr[t] = v;
    int lane = t & 63, w = t >> 6;
    int s = v;
#pragma unroll
    for (int off = 32; off; off >>= 1) s += __shfl_down(s, off);
    if (lane == 0) wsum[w] = s;
    __syncthreads();
    if (t == 0) {
        int kneed = sKrem;
        int cum = 0, w2 = 15;
        for (; w2 >= 1; --w2) { int vv = wsum[w2]; if (cum + vv >= kneed) break; cum += vv; }
        int j = 63;
        for (; j >= 1; --j) { int vv = arr[w2 * 64 + j]; if (cum + vv >= kneed) break; cum += vv; }
        int bin = c * 1024 + w2 * 64 + j;
        if (stage == 0) { ctrl[3] = bin; ctrl[4] = kneed - cum; }
        else {
            ctrl[0] = (int)((((unsigned)ctrl[3]) << 16) | (unsigned)bin);
            ctrl[2] = kneed - cum;
        }
    }
}

// ---------- fused count+emit+readout ----------
__global__ __launch_bounds__(1024) void k_cemit2(
        const float* __restrict__ score, const int* __restrict__ ctrl,
        int n, int knext, int* newid, int* oldid, float* garr,
        int* deg_out, int* fill, int* binsA, int* binsB,
        const float* __restrict__ hpost, float* finalv, float* maxbuf, float invk) {
    __shared__ int wG[16], wE[16];
    __shared__ int redCG[16], redCE[16];
    __shared__ int selIdx[1024];
    __shared__ float selG[1024];
    __shared__ int selCnt;
    __shared__ float redS[1024], redM[1024];
    int b = blockIdx.x, tid = threadIdx.x;
    int lane = tid & 63, wv = tid >> 6;
    unsigned T = (unsigned)ctrl[0];
    int needEq = ctrl[2];

    if (knext > 0) {
        int gt = b * 1024 + tid, nt = gridDim.x * 1024;
        for (int z = gt; z < 65536; z += nt) { binsA[z] = 0; binsB[z] = 0; }
        for (int z = gt; z < knext; z += nt) { deg_out[z] = 0; fill[z] = 0; }
    }

    // prefix recount over [0, b*1024)
    int cg_ = 0, ce_ = 0;
    int end = b << 10;
    for (int i = tid; i < end; i += 1024) {
        unsigned u = fkey(score[i]);
        cg_ += (u > T);
        ce_ += (u == T);
    }
#pragma unroll
    for (int off = 32; off; off >>= 1) {
        cg_ += __shfl_down(cg_, off);
        ce_ += __shfl_down(ce_, off);
    }
    if (lane == 0) { redCG[wv] = cg_; redCE[wv] = ce_; }
    if (tid == 0) selCnt = 0;

    int i = (b << 10) + tid;
    bool inb = (i < n);
    float sc = inb ? score[i] : 0.f;
    unsigned u = inb ? fkey(sc) : 0u;
    bool isG = inb && (u > T);
    bool isE = inb && (u == T);
    unsigned long long mG = __ballot(isG);
    unsigned long long mE = __ballot(isE);
    if (lane == 0) { wG[wv] = __popcll(mG); wE[wv] = __popcll(mE); }
    __syncthreads();

    int sGoff = 0, sEoff = 0;
#pragma unroll
    for (int w = 0; w < 16; ++w) { sGoff += redCG[w]; sEoff += redCE[w]; }
    int gW = 0, eW = 0;
    for (int w = 0; w < wv; ++w) { gW += wG[w]; eW += wE[w]; }
    unsigned long long below = (1ull << lane) - 1ull;
    int Gb = sGoff + gW + __popcll(mG & below);
    int Eb = sEoff + eW + __popcll(mE & below);
    if (inb) {
        bool sel = isG || (isE && (Eb < needEq));
        if (sel) {
            int j = Gb + min(Eb, needEq);
            newid[i] = j;
            oldid[j] = i;
            float g = tanhf(sc);
            garr[j] = g;
            int p = atomicAdd(&selCnt, 1);
            selIdx[p] = i;
            selG[p] = g;
        } else {
            newid[i] = -1;
        }
    }
    __syncthreads();

    int m = selCnt;
    int grp = tid >> 7, c = tid & 127;
    float sum = 0.f, mx = NEG_HUGE;
    for (int r = grp; r < m; r += 8) {
        float v = hpost[(size_t)selIdx[r] * 128 + c] * selG[r];
        sum += v;
        mx = fmaxf(mx, v);
    }
    redS[tid] = sum;
    redM[tid] = mx;
    __syncthreads();
    if (tid < 128) {
        float s2 = 0.f, m2 = NEG_HUGE;
#pragma unroll
        for (int g2 = 0; g2 < 8; ++g2) {
            s2 += redS[g2 * 128 + tid];
            m2 = fmaxf(m2, redM[g2 * 128 + tid]);
        }
        atomicAdd(&finalv[tid], s2 * invk);
        atomicMaxF(&maxbuf[tid], m2);
    }
}

// ---------- MLP: 3 parallel kernels (multi-block — single-block fusion was a
// 65us serialization: 1 CU streaming 2.4MB of weights; measured R12) ----------
__global__ void k_mlp1(const float* __restrict__ finalv, const float* __restrict__ maxbuf,
                       const float* __restrict__ seq, const float* __restrict__ W1,
                       float* f1raw) {
    int o = threadIdx.x;             // 256
    int j0 = blockIdx.x * 128;       // 10 blocks
    float acc = 0.f;
    for (int jj = 0; jj < 128; ++jj) {
        int j = j0 + jj;
        float fv;
        if (j < 128) fv = finalv[j];
        else if (j < 256) fv = maxbuf[j - 128] + maxbuf[j] + maxbuf[j + 128];
        else fv = seq[j - 256];
        acc = fmaf(fv, W1[(size_t)j * 256 + o], acc);
    }
    atomicAdd(&f1raw[o], acc);
}

__global__ void k_mlp2(const float* __restrict__ f1raw, const float* __restrict__ b1,
                       const float* __restrict__ W2, const float* __restrict__ bb2,
                       float* f2v) {
    __shared__ float f1s[256];
    int t = threadIdx.x;  // 128
    f1s[t] = fmaxf(f1raw[t] + b1[t], 0.f);
    f1s[t + 128] = fmaxf(f1raw[t + 128] + b1[t + 128], 0.f);
    __syncthreads();
    float acc = 0.f;
    for (int j = 0; j < 256; ++j)
        acc = fmaf(f1s[j], W2[(size_t)j * 128 + t], acc);
    f2v[t] = fmaxf(acc + bb2[t], 0.f);
}

__global__ void k_mlp3(const float* __restrict__ f2v, const float* __restrict__ W3,
                       const float* __restrict__ b3, float* out) {
    __shared__ float f2s[128];
    int t = threadIdx.x;  // 128
    f2s[t] = f2v[t];
    __syncthreads();
    int col = blockIdx.x * 128 + t;  // 16 blocks
    float acc = 0.f;
    for (int j = 0; j < 128; ++j)
        acc = fmaf(f2s[j], W3[(size_t)j * 2048 + col], acc);
    out[col] = acc + b3[col];
}

// ---------- host ----------
extern "C" void kernel_launch(void* const* d_in, const int* in_sizes, int n_in,
                              void* d_out, int out_size, void* d_ws, size_t ws_size,
                              hipStream_t stream) {
    (void)in_sizes; (void)n_in; (void)out_size; (void)ws_size;
    const float* feat = (const float*)d_in[0];
    const float* seq  = (const float*)d_in[1];
    const int* src = (const int*)d_in[2];
    const int* dst = (const int*)d_in[3];
    // d_in[4], d_in[5]: label_src/label_dst — dead code in reference, unused.
    const float *cW[3], *cb[3], *sW[3], *sb[3];
    for (int b = 0; b < 3; ++b) {
        cW[b] = (const float*)d_in[6 + 4 * b];
        cb[b] = (const float*)d_in[7 + 4 * b];
        sW[b] = (const float*)d_in[8 + 4 * b];
        sb[b] = (const float*)d_in[9 + 4 * b];
    }
    const float* lin1W = (const float*)d_in[18];
    const float* lin1b = (const float*)d_in[19];
    const float* lin2W = (const float*)d_in[20];
    const float* lin2b = (const float*)d_in[21];
    const float* lin3W = (const float*)d_in[22];
    const float* lin3b = (const float*)d_in[23];
    float* out = (float*)d_out;

    char* p = (char*)d_ws;
    size_t off = 0;
    auto alloc = [&](size_t bytes) -> void* {
        void* r = p + off;
        off = (off + bytes + 255) & ~(size_t)255;
        return r;
    };
    unsigned short* hpre = (unsigned short*)alloc((size_t)N0 * 128 * 2);  // bf16
    float* hpost  = (float*)alloc((size_t)N0 * 128 * 4);
    float* hs     = (float*)alloc((size_t)N0 * 4);
    float* score  = (float*)alloc((size_t)N0 * 4);
    int* deg_out  = (int*)alloc((size_t)N0 * 4);
    int* fill     = (int*)alloc((size_t)N0 * 4);
    unsigned* dp_s = (unsigned*)alloc((size_t)HSLICE * N0 * 4);  // src partials (6.4MB)
    unsigned* dp_d = (unsigned*)alloc((size_t)HSLICE * N0 * 4);  // dst partials/offsets
    int2* epair1  = (int2*)alloc((size_t)NEDGE * 8);   // compacted level-1 edges
    int* csr_src  = (int*)alloc((size_t)N0 * STRIDE * 4);
    int* newid    = (int*)alloc((size_t)N0 * 4);
    int* oldid    = (int*)alloc((size_t)25000 * 4);
    float* garr   = (float*)alloc((size_t)25000 * 4);
    float* maxbuf = (float*)alloc(3 * 128 * 4);
    float* finalv = (float*)alloc(256 * 4);
    float* f1raw  = (float*)alloc(256 * 4);
    float* f2v    = (float*)alloc(128 * 4);
    int* ctrl     = (int*)alloc(64 * 4);
    int* binsA    = (int*)alloc(65536 * 4);
    int* binsB    = (int*)alloc(65536 * 4);
    // epair2 lives only between L2-rmbuild and consumption; hpre is dead then.
    int2* epair2  = (int2*)hpre;

    const int nb[3] = {50000, 25000, 12500};
    const int kb[3] = {25000, 12500, 6250};

    k_init<<<256, 256, 0, stream>>>(finalv, f1raw, deg_out, fill, binsA, binsB,
                                    maxbuf, ctrl);

    for (int b = 0; b < 3; ++b) {
        int n = nb[b], k = kb[b];
        int B = (n + 1023) / 1024;
        if (b == 0) {
            k_hist2<<<HSLICE * 8, 1024, 0, stream>>>(src, dst, dp_s, dp_d);
            k_dsum<<<(N0 + 255) / 256, 256, 0, stream>>>(dp_s, dp_d, deg_out, fill);
            k_fill<<<HSLICE * 8, 1024, 0, stream>>>(src, dst, dp_d, csr_src);
        } else if (b == 1) {
            k_rmbuild<<<(NEDGE + 255) / 256, 256, 0, stream>>>(
                src, dst, (const int2*)0, 0, ctrl, -1, newid, epair1, ctrl + 8,
                deg_out, fill, csr_src);
        } else {
            k_rmbuild<<<(NEDGE + 255) / 256, 256, 0, stream>>>(
                (const int*)0, (const int*)0, epair1, 1, ctrl, 8, newid, epair2, ctrl + 9,
                deg_out, fill, csr_src);
        }
        k_gemm<<<(n + 63) / 64, 256, 0, stream>>>(feat, hpost, oldid, garr, deg_out, cW[b],
                                                  hpre, n, (b > 0) ? nb[b - 1] : 1,
                                                  (b == 0) ? 0 : 1);
        k_agg_conv<<<(n + 3) / 4, 256, 0, stream>>>(hpre, fill, deg_out, csr_src, cb[b],
                                                    sW[b], hpost, hs, n);
        k_score_hist<<<(n + 255) / 256, 256, 0, stream>>>(hs, fill, csr_src, sb[b],
                                                          score, binsA, n);
        k_rpick<<<1, 1024, 0, stream>>>(0, k, ctrl, binsA);
        k_rhist2<<<128, 256, 0, stream>>>(score, ctrl, n, binsB);
        k_rpick<<<1, 1024, 0, stream>>>(1, k, ctrl, binsB);
        k_cemit2<<<B, 1024, 0, stream>>>(score, ctrl, n, (b < 2) ? kb[b] : 0,
                                         newid, oldid, garr, deg_out, fill, binsA, binsB,
                                         hpost, finalv, maxbuf + b * 128,
                                         1.0f / (float)k);
    }

    k_mlp1<<<10, 256, 0, stream>>>(finalv, maxbuf, seq, lin1W, f1raw);
    k_mlp2<<<1, 128, 0, stream>>>(f1raw, lin1b, lin2W, lin2b, f2v);
    k_mlp3<<<16, 128, 0, stream>>>(f2v, lin3W, lin3b, out);
}

// Round 17
// 524.969 us; speedup vs baseline: 1.1375x; 1.0472x over previous
//
#include <hip/hip_runtime.h>
#include <hip/hip_bf16.h>
#include <cmath>

#define N0 50000
#define NEDGE 800000
#define NEG_HUGE -3.402823466e38f
#define STRIDE 128   // max degree slots per node (Poisson(16): P(deg>=128) ~ 0)
#define HBINS 6250   // histogram bins per range (8 ranges x 6250 = N0)
#define HSLICE 32    // edge slices; blockIdx = slice*8 + range -> range r on XCD r

typedef int i32x4 __attribute__((ext_vector_type(4)));
typedef __attribute__((ext_vector_type(8))) short short8v;   // 8 bf16 = 4 VGPR
typedef __attribute__((ext_vector_type(4))) float f32x4;

// ---------- helpers ----------
__device__ inline float b2f(unsigned short u) { return __uint_as_float(((unsigned)u) << 16); }

__device__ inline unsigned short f2b(float f) {
    __hip_bfloat16 h = __float2bfloat16(f);
    return *(unsigned short*)&h;
}

__device__ inline unsigned fkey(float f) {
    unsigned b = __float_as_uint(f);
    if (b == 0x80000000u) b = 0u;  // canonicalize -0 -> +0
    return (b & 0x80000000u) ? ~b : (b | 0x80000000u);
}

__device__ inline void atomicMaxF(float* a, float v) {
    if (v >= 0.f) atomicMax((int*)a, __float_as_int(v));
    else          atomicMin((unsigned int*)a, __float_as_uint(v));
}

// ---------- init: zero counters / accumulators / bins / maxbuf / edge counters ----------
__global__ void k_init(float* finalv, float* f1raw, int* deg_out, int* fill,
                       int* binsA, int* binsB, float* maxbuf, int* ctrl) {
    int i = blockIdx.x * blockDim.x + threadIdx.x;   // 256 x 256 = 65536
    if (i < 256) { finalv[i] = 0.f; f1raw[i] = 0.f; }
    if (i < 384) maxbuf[i] = NEG_HUGE;
    if (i < N0) { deg_out[i] = 0; fill[i] = 0; }
    if (i < 65536) { binsA[i] = 0; binsB[i] = 0; }
    if (i < 2) ctrl[8 + i] = 0;
}

// ---------- L0 dual histogram (src + dst): LDS-privatized, ZERO global atomics ----------
// 256 blocks = 32 slices x 8 node-ranges; blockIdx = slice*8 + r so all blocks
// of range r land on XCD r (round-robin) -> XCD-local partial writes.
__global__ __launch_bounds__(1024) void k_hist2(
        const int* __restrict__ esrc, const int* __restrict__ edst,
        unsigned* __restrict__ dp_s, unsigned* __restrict__ dp_d) {
    __shared__ unsigned hist_s[HBINS];
    __shared__ unsigned hist_d[HBINS];
    int b = blockIdx.x;
    int r = b & 7;           // node range: [r*HBINS, (r+1)*HBINS)
    int slice = b >> 3;      // 0..31
    for (int i = threadIdx.x; i < HBINS; i += 1024) { hist_s[i] = 0; hist_d[i] = 0; }
    __syncthreads();
    int lo = r * HBINS;
    int base = slice * (NEDGE / HSLICE);   // 25000-edge slice
    for (int e = threadIdx.x * 4; e < NEDGE / HSLICE; e += 4096) {
        i32x4 sv = __builtin_nontemporal_load((const i32x4*)(esrc + base + e));
        i32x4 dv = __builtin_nontemporal_load((const i32x4*)(edst + base + e));
        int ss[4] = {sv.x, sv.y, sv.z, sv.w};
        int dd[4] = {dv.x, dv.y, dv.z, dv.w};
#pragma unroll
        for (int q = 0; q < 4; ++q) {
            unsigned ls = (unsigned)(ss[q] - lo);
            if (ls < (unsigned)HBINS) atomicAdd(&hist_s[ls], 1u);
            unsigned ld = (unsigned)(dd[q] - lo);
            if (ld < (unsigned)HBINS) atomicAdd(&hist_d[ld], 1u);
        }
    }
    __syncthreads();
    for (int i = threadIdx.x; i < HBINS; i += 1024) {
        dp_s[(size_t)slice * N0 + lo + i] = hist_s[i];
        dp_d[(size_t)slice * N0 + lo + i] = hist_d[i];
    }
}

// ---------- totals + exclusive slice offsets ----------
__global__ void k_dsum(const unsigned* __restrict__ dp_s, unsigned* dp_d,
                       int* deg_out, int* fill) {
    int v = blockIdx.x * 256 + threadIdx.x;
    if (v >= N0) return;
    unsigned s = 0;
#pragma unroll
    for (int q = 0; q < HSLICE; ++q) s += dp_s[(size_t)q * N0 + v];
    deg_out[v] = (int)s;
    unsigned off = 0;
#pragma unroll
    for (int q = 0; q < HSLICE; ++q) {
        unsigned t = dp_d[(size_t)q * N0 + v];
        dp_d[(size_t)q * N0 + v] = off;
        off += t;
    }
    fill[v] = (int)off;
}

// ---------- L0 CSR fill via LDS cursors: ZERO global atomics ----------
// (R15/R16 verified: WRITE 48.5 -> 3.8 MB; 256 blocks fills the chip.)
__global__ __launch_bounds__(1024) void k_fill(
        const int* __restrict__ esrc, const int* __restrict__ edst,
        const unsigned* __restrict__ foff, int* csr_src) {
    __shared__ unsigned cur[HBINS];
    int b = blockIdx.x;
    int r = b & 7;
    int slice = b >> 3;
    int lo = r * HBINS;
    for (int i = threadIdx.x; i < HBINS; i += 1024)
        cur[i] = foff[(size_t)slice * N0 + lo + i];
    __syncthreads();
    int base = slice * (NEDGE / HSLICE);
    for (int e = threadIdx.x * 4; e < NEDGE / HSLICE; e += 4096) {
        i32x4 sv = __builtin_nontemporal_load((const i32x4*)(esrc + base + e));
        i32x4 dv = __builtin_nontemporal_load((const i32x4*)(edst + base + e));
        int ss[4] = {sv.x, sv.y, sv.z, sv.w};
        int dd[4] = {dv.x, dv.y, dv.z, dv.w};
#pragma unroll
        for (int q = 0; q < 4; ++q) {
            unsigned loc = (unsigned)(dd[q] - lo);
            if (loc < (unsigned)HBINS) {
                unsigned pos = atomicAdd(&cur[loc], 1u);
                if (pos < STRIDE) csr_src[(size_t)dd[q] * STRIDE + pos] = ss[q];
            }
        }
    }
}

// ---------- fused remap + compact + build (levels 1,2) ----------
// 1024-thread blocks: outcnt is ONE same-address device atomic per block
// (~11ns serialized each, R3-calibrated). 256-thr blocks = 3125 atomics
// ~= 35us serial chain — the R16-measured 46us; 1024-thr = 782 -> ~9us.
__global__ __launch_bounds__(1024) void k_rmbuild(
        const int* __restrict__ esrc, const int* __restrict__ edst,
        const int2* __restrict__ ein, int use_pair,
        const int* __restrict__ ctrl, int slot,
        const int* __restrict__ newid,
        int2* __restrict__ eout, int* __restrict__ outcnt,
        int* deg_out, int* fill, int* csr_src) {
    __shared__ int wbase[16];
    __shared__ int blkbase;
    int E = (slot < 0) ? NEDGE : ctrl[slot];
    if (blockIdx.x * 1024 >= E) return;   // block-uniform early exit
    int i = blockIdx.x * 1024 + threadIdx.x;
    int lane = threadIdx.x & 63, w = threadIdx.x >> 6;
    int ns = -1, nd = -1;
    if (i < E) {
        int s, d;
        if (use_pair) { int2 pr = ein[i]; s = pr.x; d = pr.y; }
        else { s = esrc[i]; d = edst[i]; }
        ns = newid[s]; nd = newid[d];
    }
    bool keep = (ns >= 0) && (nd >= 0);
    unsigned long long m = __ballot(keep);
    int rank = __popcll(m & ((1ull << lane) - 1ull));
    if (lane == 0) wbase[w] = __popcll(m);
    __syncthreads();
    if (threadIdx.x == 0) {
        int tot = 0;
#pragma unroll
        for (int q = 0; q < 16; ++q) tot += wbase[q];
        blkbase = atomicAdd(outcnt, tot);
    }
    __syncthreads();
    int base = blkbase;
    for (int q = 0; q < w; ++q) base += wbase[q];
    if (keep) {
        eout[base + rank] = make_int2(ns, nd);
        atomicAdd(&deg_out[ns], 1);
        int pos = atomicAdd(&fill[nd], 1);
        if (pos < STRIDE) csr_src[(size_t)nd * STRIDE + pos] = ns;
    }
}

// ---------- MFMA GEMM: h_pre(bf16) = esc[r] * (X @ W)[r] ----------
__global__ __launch_bounds__(256) void k_gemm(
        const float* __restrict__ feat, const float* __restrict__ xprev,
        const int* __restrict__ oldid, const float* __restrict__ garr,
        const int* __restrict__ deg_out,
        const float* __restrict__ W, unsigned short* __restrict__ hpre,
        int n, int nprev, int mode) {
    __shared__ short Wt[128][136];   // [col][k]
    __shared__ short Xt[64][136];    // [row][k]
    __shared__ int ridx_s[64];
    __shared__ float esc_s[64];
    int tid = threadIdx.x;
    int r0 = blockIdx.x * 64;
    if (tid < 64) {
        int gr = r0 + tid;
        int ridx = 0; float esc = 0.f;
        if (gr < n) {
            if (mode == 0) {
                ridx = gr;
                esc = rsqrtf(fmaxf((float)deg_out[gr], 1.f));
            } else {
                int orow = oldid[gr];
                if ((unsigned)orow < (unsigned)nprev) {
                    ridx = orow;
                    esc = rsqrtf(fmaxf((float)deg_out[gr], 1.f)) * garr[gr];
                }
            }
        }
        ridx_s[tid] = ridx;
        esc_s[tid] = esc;
    }
    __syncthreads();   // ridx_s visible to X stagers
    {   // stage W -> Wt[col][k] bf16
        int col = tid & 127;
        int kh = tid >> 7;
#pragma unroll
        for (int c8 = 0; c8 < 8; ++c8) {
            int kb = kh * 64 + c8 * 8;
            unsigned short v[8];
#pragma unroll
            for (int j = 0; j < 8; ++j)
                v[j] = f2b(W[(size_t)(kb + j) * 128 + col]);
            *(uint4*)&Wt[col][kb] = *(uint4*)v;
        }
    }
    {   // stage X tile -> Xt[row][k] bf16: 4 threads/row, 32 floats each
        const float* xsrc = (mode == 0) ? feat : xprev;
        int rr = tid >> 2;
        int kx = (tid & 3) * 32;
        const float4* xp = (const float4*)(xsrc + (size_t)ridx_s[rr] * 128 + kx);
#pragma unroll
        for (int c4 = 0; c4 < 8; ++c4) {
            float4 v = xp[c4];
            unsigned short u[4];
            u[0] = f2b(v.x); u[1] = f2b(v.y); u[2] = f2b(v.z); u[3] = f2b(v.w);
            *(uint2*)&Xt[rr][kx + c4 * 4] = *(uint2*)u;
        }
    }
    __syncthreads();

    int lane = tid & 63, w = tid >> 6;
    int row16 = lane & 15;
    int ko = (lane >> 4) * 8;
    f32x4 acc[8];
#pragma unroll
    for (int t = 0; t < 8; ++t) acc[t] = (f32x4){0.f, 0.f, 0.f, 0.f};
#pragma unroll
    for (int kc = 0; kc < 4; ++kc) {
        int kbase = kc * 32 + ko;
        short8v a = *(short8v*)&Xt[w * 16 + row16][kbase];
#pragma unroll
        for (int t = 0; t < 8; ++t) {
            short8v b = *(short8v*)&Wt[t * 16 + row16][kbase];
            acc[t] = __builtin_amdgcn_mfma_f32_16x16x32_bf16(a, b, acc[t], 0, 0, 0);
        }
    }
    int rq = (lane >> 4) * 4;
    float esc[4];
#pragma unroll
    for (int r = 0; r < 4; ++r) esc[r] = esc_s[w * 16 + rq + r];
#pragma unroll
    for (int r = 0; r < 4; ++r) {
        int gr = r0 + w * 16 + rq + r;
        if (gr < n) {
            unsigned short* op = hpre + (size_t)gr * 128;
#pragma unroll
            for (int t = 0; t < 8; ++t)
                op[t * 16 + (lane & 15)] = f2b(acc[t][r] * esc[r]);
        }
    }
}

// ---------- edge aggregation: 2 rows/wave (32 lanes x ushort4 per row) ----------
__global__ __launch_bounds__(256) void k_agg_conv(
        const unsigned short* __restrict__ hpre, const int* __restrict__ fill,
        const int* __restrict__ deg_out,
        const int* __restrict__ csr_src,
        const float* __restrict__ cb, const float* __restrict__ sW,
        float* __restrict__ hpost, float* __restrict__ hs, int n) {
    int wid = threadIdx.x >> 6;
    int lane = threadIdx.x & 63;
    int d = blockIdx.x * 4 + wid;
    if (d >= n) return;
    int degin = fill[d];
    int cnt = min(degin, STRIDE);
    const int* bp = csr_src + (size_t)d * STRIDE;
    int half = lane >> 5;        // 0: even rows, 1: odd rows
    int l32 = lane & 31;
    float a0 = 0.f, a1 = 0.f, a2 = 0.f, a3 = 0.f;   // cols c = l32*4 + q
    int j = 0;
    for (; j + 8 <= cnt; j += 8) {
        int s0 = bp[j + half];
        int s1 = bp[j + 2 + half];
        int s2 = bp[j + 4 + half];
        int s3 = bp[j + 6 + half];
        ushort4 u0 = ((const ushort4*)(hpre + (size_t)s0 * 128))[l32];
        ushort4 u1 = ((const ushort4*)(hpre + (size_t)s1 * 128))[l32];
        ushort4 u2 = ((const ushort4*)(hpre + (size_t)s2 * 128))[l32];
        ushort4 u3 = ((const ushort4*)(hpre + (size_t)s3 * 128))[l32];
        a0 += (b2f(u0.x) + b2f(u1.x)) + (b2f(u2.x) + b2f(u3.x));
        a1 += (b2f(u0.y) + b2f(u1.y)) + (b2f(u2.y) + b2f(u3.y));
        a2 += (b2f(u0.z) + b2f(u1.z)) + (b2f(u2.z) + b2f(u3.z));
        a3 += (b2f(u0.w) + b2f(u1.w)) + (b2f(u2.w) + b2f(u3.w));
    }
    for (; j < cnt; j += 2) {
        int jj = j + half;
        if (jj < cnt) {
            int s0 = bp[jj];
            ushort4 u0 = ((const ushort4*)(hpre + (size_t)s0 * 128))[l32];
            a0 += b2f(u0.x); a1 += b2f(u0.y); a2 += b2f(u0.z); a3 += b2f(u0.w);
        }
    }
    // combine even/odd halves (both halves end with identical totals)
    a0 += __shfl_xor(a0, 32);
    a1 += __shfl_xor(a1, 32);
    a2 += __shfl_xor(a2, 32);
    a3 += __shfl_xor(a3, 32);
    float nd2 = rsqrtf(fmaxf((float)degin, 1.f));
    int c0 = l32 * 4;
    float h0 = fmaxf(fmaf(a0, nd2, cb[c0]), 0.f);
    float h1 = fmaxf(fmaf(a1, nd2, cb[c0 + 1]), 0.f);
    float h2 = fmaxf(fmaf(a2, nd2, cb[c0 + 2]), 0.f);
    float h3 = fmaxf(fmaf(a3, nd2, cb[c0 + 3]), 0.f);
    if (half == 0)
        ((float4*)(hpost + (size_t)d * 128))[l32] = make_float4(h0, h1, h2, h3);
    float v = h0 * sW[c0] + h1 * sW[c0 + 1] + h2 * sW[c0 + 2] + h3 * sW[c0 + 3];
#pragma unroll
    for (int off = 16; off; off >>= 1) v += __shfl_down(v, off);
    if (lane == 0) hs[d] = v * rsqrtf(fmaxf((float)deg_out[d], 1.f));  // pre-scale
}

// ---------- score + radix histogram pass 1 (top 16 bits) fused; unroll-8 ----------
__global__ void k_score_hist(const float* __restrict__ hs, const int* __restrict__ fill,
                             const int* __restrict__ csr_src,
                             const float* __restrict__ sb, float* score,
                             int* binsA, int n) {
    int d = blockIdx.x * blockDim.x + threadIdx.x;
    if (d >= n) return;
    int degin = fill[d];
    int cnt = min(degin, STRIDE);
    const int* bp = csr_src + (size_t)d * STRIDE;
    float sum = 0.f;
    int j = 0;
    for (; j + 8 <= cnt; j += 8) {
        int4 s0 = *(const int4*)(bp + j);
        int4 s1 = *(const int4*)(bp + j + 4);
        sum += ((hs[s0.x] + hs[s0.y]) + (hs[s0.z] + hs[s0.w])) +
               ((hs[s1.x] + hs[s1.y]) + (hs[s1.z] + hs[s1.w]));
    }
    for (; j + 4 <= cnt; j += 4) {
        int4 ss = *(const int4*)(bp + j);
        sum += (hs[ss.x] + hs[ss.y]) + (hs[ss.z] + hs[ss.w]);
    }
    for (; j < cnt; ++j) sum += hs[bp[j]];
    float sc = rsqrtf(fmaxf((float)degin, 1.f)) * sum + sb[0];
    score[d] = sc;
    atomicAdd(&binsA[fkey(sc) >> 16], 1);
}

// ---------- radix histogram pass 2 (low 16 bits of matching prefix) ----------
__global__ void k_rhist2(const float* __restrict__ score, const int* __restrict__ ctrl,
                         int n, int* binsB) {
    unsigned p16 = (unsigned)ctrl[3];
    for (int i = blockIdx.x * 256 + threadIdx.x; i < n; i += gridDim.x * 256) {
        unsigned u = fkey(score[i]);
        if ((u >> 16) == p16) atomicAdd(&binsB[u & 0xFFFFu], 1);
    }
}

// ---------- radix pick with integrated chunk sums: 1 block 1024 thr ----------
__global__ void k_rpick(int stage, int k0, int* ctrl, const int* __restrict__ bins) {
    __shared__ int gs[64];
    __shared__ int arr[1024];
    __shared__ int wsum[16];
    __shared__ int sChunk, sKrem;
    int t = threadIdx.x;  // 1024
    {   // chunk sums: 16 threads per chunk of 1024 bins, 16 int4 each
        int c = t >> 4, sub = t & 15;
        const int4* p4 = (const int4*)(bins + (size_t)c * 1024);
        int s = 0;
#pragma unroll
        for (int q = 0; q < 16; ++q) {
            int4 v = p4[q * 16 + sub];
            s += v.x + v.y + v.z + v.w;
        }
#pragma unroll
        for (int off = 8; off; off >>= 1) s += __shfl_down(s, off, 16);
        if (sub == 0) gs[c] = s;
    }
    __syncthreads();
    if (t == 0) {
        int kneed = (stage == 0) ? k0 : ctrl[4];
        int cum = 0, c = 63;
        for (; c >= 1; --c) { int v = gs[c]; if (cum + v >= kneed) break; cum += v; }
        sChunk = c; sKrem = kneed - cum;
    }
    __syncthreads();
    int c = sChunk;
    int v = bins[(size_t)c * 1024 + t];
    arr[t] = v;
    int lane = t & 63, w = t >> 6;
    int s = v;
#pragma unroll
    for (int off = 32; off; off >>= 1) s += __shfl_down(s, off);
    if (lane == 0) wsum[w] = s;
    __syncthreads();
    if (t == 0) {
        int kneed = sKrem;
        int cum = 0, w2 = 15;
        for (; w2 >= 1; --w2) { int vv = wsum[w2]; if (cum + vv >= kneed) break; cum += vv; }
        int j = 63;
        for (; j >= 1; --j) { int vv = arr[w2 * 64 + j]; if (cum + vv >= kneed) break; cum += vv; }
        int bin = c * 1024 + w2 * 64 + j;
        if (stage == 0) { ctrl[3] = bin; ctrl[4] = kneed - cum; }
        else {
            ctrl[0] = (int)((((unsigned)ctrl[3]) << 16) | (unsigned)bin);
            ctrl[2] = kneed - cum;
        }
    }
}

// ---------- fused count+emit+readout ----------
__global__ __launch_bounds__(1024) void k_cemit2(
        const float* __restrict__ score, const int* __restrict__ ctrl,
        int n, int knext, int* newid, int* oldid, float* garr,
        int* deg_out, int* fill, int* binsA, int* binsB,
        const float* __restrict__ hpost, float* finalv, float* maxbuf, float invk) {
    __shared__ int wG[16], wE[16];
    __shared__ int redCG[16], redCE[16];
    __shared__ int selIdx[1024];
    __shared__ float selG[1024];
    __shared__ int selCnt;
    __shared__ float redS[1024], redM[1024];
    int b = blockIdx.x, tid = threadIdx.x;
    int lane = tid & 63, wv = tid >> 6;
    unsigned T = (unsigned)ctrl[0];
    int needEq = ctrl[2];

    if (knext > 0) {
        int gt = b * 1024 + tid, nt = gridDim.x * 1024;
        for (int z = gt; z < 65536; z += nt) { binsA[z] = 0; binsB[z] = 0; }
        for (int z = gt; z < knext; z += nt) { deg_out[z] = 0; fill[z] = 0; }
    }

    // prefix recount over [0, b*1024)
    int cg_ = 0, ce_ = 0;
    int end = b << 10;
    for (int i = tid; i < end; i += 1024) {
        unsigned u = fkey(score[i]);
        cg_ += (u > T);
        ce_ += (u == T);
    }
#pragma unroll
    for (int off = 32; off; off >>= 1) {
        cg_ += __shfl_down(cg_, off);
        ce_ += __shfl_down(ce_, off);
    }
    if (lane == 0) { redCG[wv] = cg_; redCE[wv] = ce_; }
    if (tid == 0) selCnt = 0;

    int i = (b << 10) + tid;
    bool inb = (i < n);
    float sc = inb ? score[i] : 0.f;
    unsigned u = inb ? fkey(sc) : 0u;
    bool isG = inb && (u > T);
    bool isE = inb && (u == T);
    unsigned long long mG = __ballot(isG);
    unsigned long long mE = __ballot(isE);
    if (lane == 0) { wG[wv] = __popcll(mG); wE[wv] = __popcll(mE); }
    __syncthreads();

    int sGoff = 0, sEoff = 0;
#pragma unroll
    for (int w = 0; w < 16; ++w) { sGoff += redCG[w]; sEoff += redCE[w]; }
    int gW = 0, eW = 0;
    for (int w = 0; w < wv; ++w) { gW += wG[w]; eW += wE[w]; }
    unsigned long long below = (1ull << lane) - 1ull;
    int Gb = sGoff + gW + __popcll(mG & below);
    int Eb = sEoff + eW + __popcll(mE & below);
    if (inb) {
        bool sel = isG || (isE && (Eb < needEq));
        if (sel) {
            int j = Gb + min(Eb, needEq);
            newid[i] = j;
            oldid[j] = i;
            float g = tanhf(sc);
            garr[j] = g;
            int p = atomicAdd(&selCnt, 1);
            selIdx[p] = i;
            selG[p] = g;
        } else {
            newid[i] = -1;
        }
    }
    __syncthreads();

    int m = selCnt;
    int grp = tid >> 7, c = tid & 127;
    float sum = 0.f, mx = NEG_HUGE;
    for (int r = grp; r < m; r += 8) {
        float v = hpost[(size_t)selIdx[r] * 128 + c] * selG[r];
        sum += v;
        mx = fmaxf(mx, v);
    }
    redS[tid] = sum;
    redM[tid] = mx;
    __syncthreads();
    if (tid < 128) {
        float s2 = 0.f, m2 = NEG_HUGE;
#pragma unroll
        for (int g2 = 0; g2 < 8; ++g2) {
            s2 += redS[g2 * 128 + tid];
            m2 = fmaxf(m2, redM[g2 * 128 + tid]);
        }
        atomicAdd(&finalv[tid], s2 * invk);
        atomicMaxF(&maxbuf[tid], m2);
    }
}

// ---------- MLP: 3 parallel kernels (multi-block — single-block fusion was a
// 65us serialization: 1 CU streaming 2.4MB of weights; measured R12) ----------
__global__ void k_mlp1(const float* __restrict__ finalv, const float* __restrict__ maxbuf,
                       const float* __restrict__ seq, const float* __restrict__ W1,
                       float* f1raw) {
    int o = threadIdx.x;             // 256
    int j0 = blockIdx.x * 128;       // 10 blocks
    float acc = 0.f;
    for (int jj = 0; jj < 128; ++jj) {
        int j = j0 + jj;
        float fv;
        if (j < 128) fv = finalv[j];
        else if (j < 256) fv = maxbuf[j - 128] + maxbuf[j] + maxbuf[j + 128];
        else fv = seq[j - 256];
        acc = fmaf(fv, W1[(size_t)j * 256 + o], acc);
    }
    atomicAdd(&f1raw[o], acc);
}

__global__ void k_mlp2(const float* __restrict__ f1raw, const float* __restrict__ b1,
                       const float* __restrict__ W2, const float* __restrict__ bb2,
                       float* f2v) {
    __shared__ float f1s[256];
    int t = threadIdx.x;  // 128
    f1s[t] = fmaxf(f1raw[t] + b1[t], 0.f);
    f1s[t + 128] = fmaxf(f1raw[t + 128] + b1[t + 128], 0.f);
    __syncthreads();
    float acc = 0.f;
    for (int j = 0; j < 256; ++j)
        acc = fmaf(f1s[j], W2[(size_t)j * 128 + t], acc);
    f2v[t] = fmaxf(acc + bb2[t], 0.f);
}

__global__ void k_mlp3(const float* __restrict__ f2v, const float* __restrict__ W3,
                       const float* __restrict__ b3, float* out) {
    __shared__ float f2s[128];
    int t = threadIdx.x;  // 128
    f2s[t] = f2v[t];
    __syncthreads();
    int col = blockIdx.x * 128 + t;  // 16 blocks
    float acc = 0.f;
    for (int j = 0; j < 128; ++j)
        acc = fmaf(f2s[j], W3[(size_t)j * 2048 + col], acc);
    out[col] = acc + b3[col];
}

// ---------- host ----------
extern "C" void kernel_launch(void* const* d_in, const int* in_sizes, int n_in,
                              void* d_out, int out_size, void* d_ws, size_t ws_size,
                              hipStream_t stream) {
    (void)in_sizes; (void)n_in; (void)out_size; (void)ws_size;
    const float* feat = (const float*)d_in[0];
    const float* seq  = (const float*)d_in[1];
    const int* src = (const int*)d_in[2];
    const int* dst = (const int*)d_in[3];
    // d_in[4], d_in[5]: label_src/label_dst — dead code in reference, unused.
    const float *cW[3], *cb[3], *sW[3], *sb[3];
    for (int b = 0; b < 3; ++b) {
        cW[b] = (const float*)d_in[6 + 4 * b];
        cb[b] = (const float*)d_in[7 + 4 * b];
        sW[b] = (const float*)d_in[8 + 4 * b];
        sb[b] = (const float*)d_in[9 + 4 * b];
    }
    const float* lin1W = (const float*)d_in[18];
    const float* lin1b = (const float*)d_in[19];
    const float* lin2W = (const float*)d_in[20];
    const float* lin2b = (const float*)d_in[21];
    const float* lin3W = (const float*)d_in[22];
    const float* lin3b = (const float*)d_in[23];
    float* out = (float*)d_out;

    char* p = (char*)d_ws;
    size_t off = 0;
    auto alloc = [&](size_t bytes) -> void* {
        void* r = p + off;
        off = (off + bytes + 255) & ~(size_t)255;
        return r;
    };
    unsigned short* hpre = (unsigned short*)alloc((size_t)N0 * 128 * 2);  // bf16
    float* hpost  = (float*)alloc((size_t)N0 * 128 * 4);
    float* hs     = (float*)alloc((size_t)N0 * 4);
    float* score  = (float*)alloc((size_t)N0 * 4);
    int* deg_out  = (int*)alloc((size_t)N0 * 4);
    int* fill     = (int*)alloc((size_t)N0 * 4);
    unsigned* dp_s = (unsigned*)alloc((size_t)HSLICE * N0 * 4);  // src partials (6.4MB)
    unsigned* dp_d = (unsigned*)alloc((size_t)HSLICE * N0 * 4);  // dst partials/offsets
    int2* epair1  = (int2*)alloc((size_t)NEDGE * 8);   // compacted level-1 edges
    int* csr_src  = (int*)alloc((size_t)N0 * STRIDE * 4);
    int* newid    = (int*)alloc((size_t)N0 * 4);
    int* oldid    = (int*)alloc((size_t)25000 * 4);
    float* garr   = (float*)alloc((size_t)25000 * 4);
    float* maxbuf = (float*)alloc(3 * 128 * 4);
    float* finalv = (float*)alloc(256 * 4);
    float* f1raw  = (float*)alloc(256 * 4);
    float* f2v    = (float*)alloc(128 * 4);
    int* ctrl     = (int*)alloc(64 * 4);
    int* binsA    = (int*)alloc(65536 * 4);
    int* binsB    = (int*)alloc(65536 * 4);
    // epair2 lives only between L2-rmbuild and consumption; hpre is dead then.
    int2* epair2  = (int2*)hpre;

    const int nb[3] = {50000, 25000, 12500};
    const int kb[3] = {25000, 12500, 6250};

    k_init<<<256, 256, 0, stream>>>(finalv, f1raw, deg_out, fill, binsA, binsB,
                                    maxbuf, ctrl);

    for (int b = 0; b < 3; ++b) {
        int n = nb[b], k = kb[b];
        int B = (n + 1023) / 1024;
        if (b == 0) {
            k_hist2<<<HSLICE * 8, 1024, 0, stream>>>(src, dst, dp_s, dp_d);
            k_dsum<<<(N0 + 255) / 256, 256, 0, stream>>>(dp_s, dp_d, deg_out, fill);
            k_fill<<<HSLICE * 8, 1024, 0, stream>>>(src, dst, dp_d, csr_src);
        } else if (b == 1) {
            k_rmbuild<<<(NEDGE + 1023) / 1024, 1024, 0, stream>>>(
                src, dst, (const int2*)0, 0, ctrl, -1, newid, epair1, ctrl + 8,
                deg_out, fill, csr_src);
        } else {
            k_rmbuild<<<(NEDGE + 1023) / 1024, 1024, 0, stream>>>(
                (const int*)0, (const int*)0, epair1, 1, ctrl, 8, newid, epair2, ctrl + 9,
                deg_out, fill, csr_src);
        }
        k_gemm<<<(n + 63) / 64, 256, 0, stream>>>(feat, hpost, oldid, garr, deg_out, cW[b],
                                                  hpre, n, (b > 0) ? nb[b - 1] : 1,
                                                  (b == 0) ? 0 : 1);
        k_agg_conv<<<(n + 3) / 4, 256, 0, stream>>>(hpre, fill, deg_out, csr_src, cb[b],
                                                    sW[b], hpost, hs, n);
        k_score_hist<<<(n + 255) / 256, 256, 0, stream>>>(hs, fill, csr_src, sb[b],
                                                          score, binsA, n);
        k_rpick<<<1, 1024, 0, stream>>>(0, k, ctrl, binsA);
        k_rhist2<<<128, 256, 0, stream>>>(score, ctrl, n, binsB);
        k_rpick<<<1, 1024, 0, stream>>>(1, k, ctrl, binsB);
        k_cemit2<<<B, 1024, 0, stream>>>(score, ctrl, n, (b < 2) ? kb[b] : 0,
                                         newid, oldid, garr, deg_out, fill, binsA, binsB,
                                         hpost, finalv, maxbuf + b * 128,
                                         1.0f / (float)k);
    }

    k_mlp1<<<10, 256, 0, stream>>>(finalv, maxbuf, seq, lin1W, f1raw);
    k_mlp2<<<1, 128, 0, stream>>>(f1raw, lin1b, lin2W, lin2b, f2v);
    k_mlp3<<<16, 128, 0, stream>>>(f2v, lin3W, lin3b, out);
}

// Round 18
// 521.429 us; speedup vs baseline: 1.1452x; 1.0068x over previous
//
#include <hip/hip_runtime.h>
#include <hip/hip_bf16.h>
#include <cmath>

#define N0 50000
#define NEDGE 800000
#define NEG_HUGE -3.402823466e38f
#define STRIDE 128   // max degree slots per node (Poisson(16): P(deg>=128) ~ 0)
#define HBINS 6250   // histogram bins per range (8 ranges x 6250 = N0)
#define HSLICE 32    // edge slices; blockIdx = slice*8 + range -> range r on XCD r

typedef int i32x4 __attribute__((ext_vector_type(4)));
typedef __attribute__((ext_vector_type(8))) short short8v;   // 8 bf16 = 4 VGPR
typedef __attribute__((ext_vector_type(4))) float f32x4;

// ---------- helpers ----------
__device__ inline float b2f(unsigned short u) { return __uint_as_float(((unsigned)u) << 16); }

__device__ inline unsigned short f2b(float f) {
    __hip_bfloat16 h = __float2bfloat16(f);
    return *(unsigned short*)&h;
}

__device__ inline unsigned fkey(float f) {
    unsigned b = __float_as_uint(f);
    if (b == 0x80000000u) b = 0u;  // canonicalize -0 -> +0
    return (b & 0x80000000u) ? ~b : (b | 0x80000000u);
}

__device__ inline void atomicMaxF(float* a, float v) {
    if (v >= 0.f) atomicMax((int*)a, __float_as_int(v));
    else          atomicMin((unsigned int*)a, __float_as_uint(v));
}

// ---------- init: zero accumulators / bins / maxbuf / edge counters ----------
// deg_out/fill NOT zeroed here: L0's k_dsum overwrites them before any read.
__global__ void k_init(float* finalv, float* f1raw,
                       int* binsA, int* binsB, float* maxbuf, int* ctrl) {
    int i = blockIdx.x * blockDim.x + threadIdx.x;   // 256 x 256 = 65536
    if (i < 256) { finalv[i] = 0.f; f1raw[i] = 0.f; }
    if (i < 384) maxbuf[i] = NEG_HUGE;
    if (i < 65536) { binsA[i] = 0; binsB[i] = 0; }
    if (i < 2) ctrl[8 + i] = 0;
}

// ---------- L0 dual histogram (src + dst): LDS-privatized, ZERO global atomics ----------
// 256 blocks = 32 slices x 8 node-ranges; blockIdx = slice*8 + r so all blocks
// of range r land on XCD r (round-robin) -> XCD-local partial writes.
__global__ __launch_bounds__(1024) void k_hist2(
        const int* __restrict__ esrc, const int* __restrict__ edst,
        unsigned* __restrict__ dp_s, unsigned* __restrict__ dp_d) {
    __shared__ unsigned hist_s[HBINS];
    __shared__ unsigned hist_d[HBINS];
    int b = blockIdx.x;
    int r = b & 7;           // node range: [r*HBINS, (r+1)*HBINS)
    int slice = b >> 3;      // 0..31
    for (int i = threadIdx.x; i < HBINS; i += 1024) { hist_s[i] = 0; hist_d[i] = 0; }
    __syncthreads();
    int lo = r * HBINS;
    int base = slice * (NEDGE / HSLICE);   // 25000-edge slice
    for (int e = threadIdx.x * 4; e < NEDGE / HSLICE; e += 4096) {
        i32x4 sv = __builtin_nontemporal_load((const i32x4*)(esrc + base + e));
        i32x4 dv = __builtin_nontemporal_load((const i32x4*)(edst + base + e));
        int ss[4] = {sv.x, sv.y, sv.z, sv.w};
        int dd[4] = {dv.x, dv.y, dv.z, dv.w};
#pragma unroll
        for (int q = 0; q < 4; ++q) {
            unsigned ls = (unsigned)(ss[q] - lo);
            if (ls < (unsigned)HBINS) atomicAdd(&hist_s[ls], 1u);
            unsigned ld = (unsigned)(dd[q] - lo);
            if (ld < (unsigned)HBINS) atomicAdd(&hist_d[ld], 1u);
        }
    }
    __syncthreads();
    for (int i = threadIdx.x; i < HBINS; i += 1024) {
        dp_s[(size_t)slice * N0 + lo + i] = hist_s[i];
        dp_d[(size_t)slice * N0 + lo + i] = hist_d[i];
    }
}

// ---------- totals + exclusive slice offsets ----------
__global__ void k_dsum(const unsigned* __restrict__ dp_s, unsigned* dp_d,
                       int* deg_out, int* fill) {
    int v = blockIdx.x * 256 + threadIdx.x;
    if (v >= N0) return;
    unsigned s = 0;
#pragma unroll
    for (int q = 0; q < HSLICE; ++q) s += dp_s[(size_t)q * N0 + v];
    deg_out[v] = (int)s;
    unsigned off = 0;
#pragma unroll
    for (int q = 0; q < HSLICE; ++q) {
        unsigned t = dp_d[(size_t)q * N0 + v];
        dp_d[(size_t)q * N0 + v] = off;
        off += t;
    }
    fill[v] = (int)off;
}

// ---------- L0 CSR fill via LDS cursors: ZERO global atomics ----------
// (R15/R16 verified: WRITE 48.5 -> 3.8 MB; 256 blocks fills the chip.)
__global__ __launch_bounds__(1024) void k_fill(
        const int* __restrict__ esrc, const int* __restrict__ edst,
        const unsigned* __restrict__ foff, int* csr_src) {
    __shared__ unsigned cur[HBINS];
    int b = blockIdx.x;
    int r = b & 7;
    int slice = b >> 3;
    int lo = r * HBINS;
    for (int i = threadIdx.x; i < HBINS; i += 1024)
        cur[i] = foff[(size_t)slice * N0 + lo + i];
    __syncthreads();
    int base = slice * (NEDGE / HSLICE);
    for (int e = threadIdx.x * 4; e < NEDGE / HSLICE; e += 4096) {
        i32x4 sv = __builtin_nontemporal_load((const i32x4*)(esrc + base + e));
        i32x4 dv = __builtin_nontemporal_load((const i32x4*)(edst + base + e));
        int ss[4] = {sv.x, sv.y, sv.z, sv.w};
        int dd[4] = {dv.x, dv.y, dv.z, dv.w};
#pragma unroll
        for (int q = 0; q < 4; ++q) {
            unsigned loc = (unsigned)(dd[q] - lo);
            if (loc < (unsigned)HBINS) {
                unsigned pos = atomicAdd(&cur[loc], 1u);
                if (pos < STRIDE) csr_src[(size_t)dd[q] * STRIDE + pos] = ss[q];
            }
        }
    }
}

// ---------- fused remap + compact + build (levels 1,2) ----------
// 1024-thread blocks: ONE same-address outcnt atomic per block (R16->R17:
// 3125 blocks @256thr = ~35us serial chain; 782 @1024thr fixed it).
__global__ __launch_bounds__(1024) void k_rmbuild(
        const int* __restrict__ esrc, const int* __restrict__ edst,
        const int2* __restrict__ ein, int use_pair,
        const int* __restrict__ ctrl, int slot,
        const int* __restrict__ newid,
        int2* __restrict__ eout, int* __restrict__ outcnt,
        int* deg_out, int* fill, int* csr_src) {
    __shared__ int wbase[16];
    __shared__ int blkbase;
    int E = (slot < 0) ? NEDGE : ctrl[slot];
    if (blockIdx.x * 1024 >= E) return;   // block-uniform early exit
    int i = blockIdx.x * 1024 + threadIdx.x;
    int lane = threadIdx.x & 63, w = threadIdx.x >> 6;
    int ns = -1, nd = -1;
    if (i < E) {
        int s, d;
        if (use_pair) { int2 pr = ein[i]; s = pr.x; d = pr.y; }
        else { s = esrc[i]; d = edst[i]; }
        ns = newid[s]; nd = newid[d];
    }
    bool keep = (ns >= 0) && (nd >= 0);
    unsigned long long m = __ballot(keep);
    int rank = __popcll(m & ((1ull << lane) - 1ull));
    if (lane == 0) wbase[w] = __popcll(m);
    __syncthreads();
    if (threadIdx.x == 0) {
        int tot = 0;
#pragma unroll
        for (int q = 0; q < 16; ++q) tot += wbase[q];
        blkbase = atomicAdd(outcnt, tot);
    }
    __syncthreads();
    int base = blkbase;
    for (int q = 0; q < w; ++q) base += wbase[q];
    if (keep) {
        eout[base + rank] = make_int2(ns, nd);
        atomicAdd(&deg_out[ns], 1);
        int pos = atomicAdd(&fill[nd], 1);
        if (pos < STRIDE) csr_src[(size_t)nd * STRIDE + pos] = ns;
    }
}

// ---------- MFMA GEMM: h_pre(bf16) = esc[r] * (X @ W)[r] ----------
__global__ __launch_bounds__(256) void k_gemm(
        const float* __restrict__ feat, const float* __restrict__ xprev,
        const int* __restrict__ oldid, const float* __restrict__ garr,
        const int* __restrict__ deg_out,
        const float* __restrict__ W, unsigned short* __restrict__ hpre,
        int n, int nprev, int mode) {
    __shared__ short Wt[128][136];   // [col][k]
    __shared__ short Xt[64][136];    // [row][k]
    __shared__ int ridx_s[64];
    __shared__ float esc_s[64];
    int tid = threadIdx.x;
    int r0 = blockIdx.x * 64;
    if (tid < 64) {
        int gr = r0 + tid;
        int ridx = 0; float esc = 0.f;
        if (gr < n) {
            if (mode == 0) {
                ridx = gr;
                esc = rsqrtf(fmaxf((float)deg_out[gr], 1.f));
            } else {
                int orow = oldid[gr];
                if ((unsigned)orow < (unsigned)nprev) {
                    ridx = orow;
                    esc = rsqrtf(fmaxf((float)deg_out[gr], 1.f)) * garr[gr];
                }
            }
        }
        ridx_s[tid] = ridx;
        esc_s[tid] = esc;
    }
    __syncthreads();   // ridx_s visible to X stagers
    {   // stage W -> Wt[col][k] bf16 (lane-consecutive cols: coalesced)
        int col = tid & 127;
        int kh = tid >> 7;
#pragma unroll
        for (int c8 = 0; c8 < 8; ++c8) {
            int kb = kh * 64 + c8 * 8;
            unsigned short v[8];
#pragma unroll
            for (int j = 0; j < 8; ++j)
                v[j] = f2b(W[(size_t)(kb + j) * 128 + col]);
            *(uint4*)&Wt[col][kb] = *(uint4*)v;
        }
    }
    {   // stage X tile -> Xt[row][k] bf16: 4 threads/row, 32 floats each
        const float* xsrc = (mode == 0) ? feat : xprev;
        int rr = tid >> 2;
        int kx = (tid & 3) * 32;
        const float4* xp = (const float4*)(xsrc + (size_t)ridx_s[rr] * 128 + kx);
#pragma unroll
        for (int c4 = 0; c4 < 8; ++c4) {
            float4 v = xp[c4];
            unsigned short u[4];
            u[0] = f2b(v.x); u[1] = f2b(v.y); u[2] = f2b(v.z); u[3] = f2b(v.w);
            *(uint2*)&Xt[rr][kx + c4 * 4] = *(uint2*)u;
        }
    }
    __syncthreads();

    int lane = tid & 63, w = tid >> 6;
    int row16 = lane & 15;
    int ko = (lane >> 4) * 8;
    f32x4 acc[8];
#pragma unroll
    for (int t = 0; t < 8; ++t) acc[t] = (f32x4){0.f, 0.f, 0.f, 0.f};
#pragma unroll
    for (int kc = 0; kc < 4; ++kc) {
        int kbase = kc * 32 + ko;
        short8v a = *(short8v*)&Xt[w * 16 + row16][kbase];
#pragma unroll
        for (int t = 0; t < 8; ++t) {
            short8v b = *(short8v*)&Wt[t * 16 + row16][kbase];
            acc[t] = __builtin_amdgcn_mfma_f32_16x16x32_bf16(a, b, acc[t], 0, 0, 0);
        }
    }
    int rq = (lane >> 4) * 4;
    float esc[4];
#pragma unroll
    for (int r = 0; r < 4; ++r) esc[r] = esc_s[w * 16 + rq + r];
#pragma unroll
    for (int r = 0; r < 4; ++r) {
        int gr = r0 + w * 16 + rq + r;
        if (gr < n) {
            unsigned short* op = hpre + (size_t)gr * 128;
#pragma unroll
            for (int t = 0; t < 8; ++t)
                op[t * 16 + (lane & 15)] = f2b(acc[t][r] * esc[r]);
        }
    }
}

// ---------- edge aggregation: 2 rows/wave (32 lanes x ushort4 per row) ----------
__global__ __launch_bounds__(256) void k_agg_conv(
        const unsigned short* __restrict__ hpre, const int* __restrict__ fill,
        const int* __restrict__ deg_out,
        const int* __restrict__ csr_src,
        const float* __restrict__ cb, const float* __restrict__ sW,
        float* __restrict__ hpost, float* __restrict__ hs, int n) {
    int wid = threadIdx.x >> 6;
    int lane = threadIdx.x & 63;
    int d = blockIdx.x * 4 + wid;
    if (d >= n) return;
    int degin = fill[d];
    int cnt = min(degin, STRIDE);
    const int* bp = csr_src + (size_t)d * STRIDE;
    int half = lane >> 5;        // 0: even rows, 1: odd rows
    int l32 = lane & 31;
    float a0 = 0.f, a1 = 0.f, a2 = 0.f, a3 = 0.f;   // cols c = l32*4 + q
    int j = 0;
    for (; j + 8 <= cnt; j += 8) {
        int s0 = bp[j + half];
        int s1 = bp[j + 2 + half];
        int s2 = bp[j + 4 + half];
        int s3 = bp[j + 6 + half];
        ushort4 u0 = ((const ushort4*)(hpre + (size_t)s0 * 128))[l32];
        ushort4 u1 = ((const ushort4*)(hpre + (size_t)s1 * 128))[l32];
        ushort4 u2 = ((const ushort4*)(hpre + (size_t)s2 * 128))[l32];
        ushort4 u3 = ((const ushort4*)(hpre + (size_t)s3 * 128))[l32];
        a0 += (b2f(u0.x) + b2f(u1.x)) + (b2f(u2.x) + b2f(u3.x));
        a1 += (b2f(u0.y) + b2f(u1.y)) + (b2f(u2.y) + b2f(u3.y));
        a2 += (b2f(u0.z) + b2f(u1.z)) + (b2f(u2.z) + b2f(u3.z));
        a3 += (b2f(u0.w) + b2f(u1.w)) + (b2f(u2.w) + b2f(u3.w));
    }
    for (; j < cnt; j += 2) {
        int jj = j + half;
        if (jj < cnt) {
            int s0 = bp[jj];
            ushort4 u0 = ((const ushort4*)(hpre + (size_t)s0 * 128))[l32];
            a0 += b2f(u0.x); a1 += b2f(u0.y); a2 += b2f(u0.z); a3 += b2f(u0.w);
        }
    }
    // combine even/odd halves (both halves end with identical totals)
    a0 += __shfl_xor(a0, 32);
    a1 += __shfl_xor(a1, 32);
    a2 += __shfl_xor(a2, 32);
    a3 += __shfl_xor(a3, 32);
    float nd2 = rsqrtf(fmaxf((float)degin, 1.f));
    int c0 = l32 * 4;
    float h0 = fmaxf(fmaf(a0, nd2, cb[c0]), 0.f);
    float h1 = fmaxf(fmaf(a1, nd2, cb[c0 + 1]), 0.f);
    float h2 = fmaxf(fmaf(a2, nd2, cb[c0 + 2]), 0.f);
    float h3 = fmaxf(fmaf(a3, nd2, cb[c0 + 3]), 0.f);
    if (half == 0)
        ((float4*)(hpost + (size_t)d * 128))[l32] = make_float4(h0, h1, h2, h3);
    float v = h0 * sW[c0] + h1 * sW[c0 + 1] + h2 * sW[c0 + 2] + h3 * sW[c0 + 3];
#pragma unroll
    for (int off = 16; off; off >>= 1) v += __shfl_down(v, off);
    if (lane == 0) hs[d] = v * rsqrtf(fmaxf((float)deg_out[d], 1.f));  // pre-scale
}

// ---------- score + radix histogram pass 1 (top 16 bits) fused; unroll-8 ----------
__global__ void k_score_hist(const float* __restrict__ hs, const int* __restrict__ fill,
                             const int* __restrict__ csr_src,
                             const float* __restrict__ sb, float* score,
                             int* binsA, int n) {
    int d = blockIdx.x * blockDim.x + threadIdx.x;
    if (d >= n) return;
    int degin = fill[d];
    int cnt = min(degin, STRIDE);
    const int* bp = csr_src + (size_t)d * STRIDE;
    float sum = 0.f;
    int j = 0;
    for (; j + 8 <= cnt; j += 8) {
        int4 s0 = *(const int4*)(bp + j);
        int4 s1 = *(const int4*)(bp + j + 4);
        sum += ((hs[s0.x] + hs[s0.y]) + (hs[s0.z] + hs[s0.w])) +
               ((hs[s1.x] + hs[s1.y]) + (hs[s1.z] + hs[s1.w]));
    }
    for (; j + 4 <= cnt; j += 4) {
        int4 ss = *(const int4*)(bp + j);
        sum += (hs[ss.x] + hs[ss.y]) + (hs[ss.z] + hs[ss.w]);
    }
    for (; j < cnt; ++j) sum += hs[bp[j]];
    float sc = rsqrtf(fmaxf((float)degin, 1.f)) * sum + sb[0];
    score[d] = sc;
    atomicAdd(&binsA[fkey(sc) >> 16], 1);
}

// ---------- radix histogram pass 2 (low 16 bits of matching prefix) ----------
__global__ void k_rhist2(const float* __restrict__ score, const int* __restrict__ ctrl,
                         int n, int* binsB) {
    unsigned p16 = (unsigned)ctrl[3];
    for (int i = blockIdx.x * 256 + threadIdx.x; i < n; i += gridDim.x * 256) {
        unsigned u = fkey(score[i]);
        if ((u >> 16) == p16) atomicAdd(&binsB[u & 0xFFFFu], 1);
    }
}

// ---------- radix pick with integrated chunk sums: 1 block 1024 thr ----------
__global__ void k_rpick(int stage, int k0, int* ctrl, const int* __restrict__ bins) {
    __shared__ int gs[64];
    __shared__ int arr[1024];
    __shared__ int wsum[16];
    __shared__ int sChunk, sKrem;
    int t = threadIdx.x;  // 1024
    {   // chunk sums: 16 threads per chunk of 1024 bins, 16 int4 each
        int c = t >> 4, sub = t & 15;
        const int4* p4 = (const int4*)(bins + (size_t)c * 1024);
        int s = 0;
#pragma unroll
        for (int q = 0; q < 16; ++q) {
            int4 v = p4[q * 16 + sub];
            s += v.x + v.y + v.z + v.w;
        }
#pragma unroll
        for (int off = 8; off; off >>= 1) s += __shfl_down(s, off, 16);
        if (sub == 0) gs[c] = s;
    }
    __syncthreads();
    if (t == 0) {
        int kneed = (stage == 0) ? k0 : ctrl[4];
        int cum = 0, c = 63;
        for (; c >= 1; --c) { int v = gs[c]; if (cum + v >= kneed) break; cum += v; }
        sChunk = c; sKrem = kneed - cum;
    }
    __syncthreads();
    int c = sChunk;
    int v = bins[(size_t)c * 1024 + t];
    arr[t] = v;
    int lane = t & 63, w = t >> 6;
    int s = v;
#pragma unroll
    for (int off = 32; off; off >>= 1) s += __shfl_down(s, off);
    if (lane == 0) wsum[w] = s;
    __syncthreads();
    if (t == 0) {
        int kneed = sKrem;
        int cum = 0, w2 = 15;
        for (; w2 >= 1; --w2) { int vv = wsum[w2]; if (cum + vv >= kneed) break; cum += vv; }
        int j = 63;
        for (; j >= 1; --j) { int vv = arr[w2 * 64 + j]; if (cum + vv >= kneed) break; cum += vv; }
        int bin = c * 1024 + w2 * 64 + j;
        if (stage == 0) { ctrl[3] = bin; ctrl[4] = kneed - cum; }
        else {
            ctrl[0] = (int)((((unsigned)ctrl[3]) << 16) | (unsigned)bin);
            ctrl[2] = kneed - cum;
        }
    }
}

// ---------- fused count+emit+readout ----------
__global__ __launch_bounds__(1024) void k_cemit2(
        const float* __restrict__ score, const int* __restrict__ ctrl,
        int n, int knext, int* newid, int* oldid, float* garr,
        int* deg_out, int* fill, int* binsA, int* binsB,
        const float* __restrict__ hpost, float* finalv, float* maxbuf, float invk) {
    __shared__ int wG[16], wE[16];
    __shared__ int redCG[16], redCE[16];
    __shared__ int selIdx[1024];
    __shared__ float selG[1024];
    __shared__ int selCnt;
    __shared__ float redS[1024], redM[1024];
    int b = blockIdx.x, tid = threadIdx.x;
    int lane = tid & 63, wv = tid >> 6;
    unsigned T = (unsigned)ctrl[0];
    int needEq = ctrl[2];

    if (knext > 0) {
        int gt = b * 1024 + tid, nt = gridDim.x * 1024;
        for (int z = gt; z < 65536; z += nt) { binsA[z] = 0; binsB[z] = 0; }
        for (int z = gt; z < knext; z += nt) { deg_out[z] = 0; fill[z] = 0; }
    }

    // prefix recount over [0, b*1024) — float4-vectorized (base multiple of 4)
    int cg_ = 0, ce_ = 0;
    int end = b << 10;
    for (int i = tid * 4; i < end; i += 4096) {
        float4 v = *(const float4*)(score + i);
        unsigned u0 = fkey(v.x), u1 = fkey(v.y), u2 = fkey(v.z), u3 = fkey(v.w);
        cg_ += (u0 > T) + (u1 > T) + (u2 > T) + (u3 > T);
        ce_ += (u0 == T) + (u1 == T) + (u2 == T) + (u3 == T);
    }
#pragma unroll
    for (int off = 32; off; off >>= 1) {
        cg_ += __shfl_down(cg_, off);
        ce_ += __shfl_down(ce_, off);
    }
    if (lane == 0) { redCG[wv] = cg_; redCE[wv] = ce_; }
    if (tid == 0) selCnt = 0;

    int i = (b << 10) + tid;
    bool inb = (i < n);
    float sc = inb ? score[i] : 0.f;
    unsigned u = inb ? fkey(sc) : 0u;
    bool isG = inb && (u > T);
    bool isE = inb && (u == T);
    unsigned long long mG = __ballot(isG);
    unsigned long long mE = __ballot(isE);
    if (lane == 0) { wG[wv] = __popcll(mG); wE[wv] = __popcll(mE); }
    __syncthreads();

    int sGoff = 0, sEoff = 0;
#pragma unroll
    for (int w = 0; w < 16; ++w) { sGoff += redCG[w]; sEoff += redCE[w]; }
    int gW = 0, eW = 0;
    for (int w = 0; w < wv; ++w) { gW += wG[w]; eW += wE[w]; }
    unsigned long long below = (1ull << lane) - 1ull;
    int Gb = sGoff + gW + __popcll(mG & below);
    int Eb = sEoff + eW + __popcll(mE & below);
    if (inb) {
        bool sel = isG || (isE && (Eb < needEq));
        if (sel) {
            int j = Gb + min(Eb, needEq);
            newid[i] = j;
            oldid[j] = i;
            float g = tanhf(sc);
            garr[j] = g;
            int p = atomicAdd(&selCnt, 1);
            selIdx[p] = i;
            selG[p] = g;
        } else {
            newid[i] = -1;
        }
    }
    __syncthreads();

    int m = selCnt;
    int grp = tid >> 7, c = tid & 127;
    float sum = 0.f, mx = NEG_HUGE;
    for (int r = grp; r < m; r += 8) {
        float v = hpost[(size_t)selIdx[r] * 128 + c] * selG[r];
        sum += v;
        mx = fmaxf(mx, v);
    }
    redS[tid] = sum;
    redM[tid] = mx;
    __syncthreads();
    if (tid < 128) {
        float s2 = 0.f, m2 = NEG_HUGE;
#pragma unroll
        for (int g2 = 0; g2 < 8; ++g2) {
            s2 += redS[g2 * 128 + tid];
            m2 = fmaxf(m2, redM[g2 * 128 + tid]);
        }
        atomicAdd(&finalv[tid], s2 * invk);
        atomicMaxF(&maxbuf[tid], m2);
    }
}

// ---------- MLP: 3 parallel kernels (multi-block — single-block fusion was a
// 65us serialization: 1 CU streaming 2.4MB of weights; measured R12) ----------
__global__ void k_mlp1(const float* __restrict__ finalv, const float* __restrict__ maxbuf,
                       const float* __restrict__ seq, const float* __restrict__ W1,
                       float* f1raw) {
    int o = threadIdx.x;             // 256
    int j0 = blockIdx.x * 128;       // 10 blocks
    float acc = 0.f;
    for (int jj = 0; jj < 128; ++jj) {
        int j = j0 + jj;
        float fv;
        if (j < 128) fv = finalv[j];
        else if (j < 256) fv = maxbuf[j - 128] + maxbuf[j] + maxbuf[j + 128];
        else fv = seq[j - 256];
        acc = fmaf(fv, W1[(size_t)j * 256 + o], acc);
    }
    atomicAdd(&f1raw[o], acc);
}

__global__ void k_mlp2(const float* __restrict__ f1raw, const float* __restrict__ b1,
                       const float* __restrict__ W2, const float* __restrict__ bb2,
                       float* f2v) {
    __shared__ float f1s[256];
    int t = threadIdx.x;  // 128
    f1s[t] = fmaxf(f1raw[t] + b1[t], 0.f);
    f1s[t + 128] = fmaxf(f1raw[t + 128] + b1[t + 128], 0.f);
    __syncthreads();
    float acc = 0.f;
    for (int j = 0; j < 256; ++j)
        acc = fmaf(f1s[j], W2[(size_t)j * 128 + t], acc);
    f2v[t] = fmaxf(acc + bb2[t], 0.f);
}

__global__ void k_mlp3(const float* __restrict__ f2v, const float* __restrict__ W3,
                       const float* __restrict__ b3, float* out) {
    __shared__ float f2s[128];
    int t = threadIdx.x;  // 128
    f2s[t] = f2v[t];
    __syncthreads();
    int col = blockIdx.x * 128 + t;  // 16 blocks
    float acc = 0.f;
    for (int j = 0; j < 128; ++j)
        acc = fmaf(f2s[j], W3[(size_t)j * 2048 + col], acc);
    out[col] = acc + b3[col];
}

// ---------- host ----------
extern "C" void kernel_launch(void* const* d_in, const int* in_sizes, int n_in,
                              void* d_out, int out_size, void* d_ws, size_t ws_size,
                              hipStream_t stream) {
    (void)in_sizes; (void)n_in; (void)out_size; (void)ws_size;
    const float* feat = (const float*)d_in[0];
    const float* seq  = (const float*)d_in[1];
    const int* src = (const int*)d_in[2];
    const int* dst = (const int*)d_in[3];
    // d_in[4], d_in[5]: label_src/label_dst — dead code in reference, unused.
    const float *cW[3], *cb[3], *sW[3], *sb[3];
    for (int b = 0; b < 3; ++b) {
        cW[b] = (const float*)d_in[6 + 4 * b];
        cb[b] = (const float*)d_in[7 + 4 * b];
        sW[b] = (const float*)d_in[8 + 4 * b];
        sb[b] = (const float*)d_in[9 + 4 * b];
    }
    const float* lin1W = (const float*)d_in[18];
    const float* lin1b = (const float*)d_in[19];
    const float* lin2W = (const float*)d_in[20];
    const float* lin2b = (const float*)d_in[21];
    const float* lin3W = (const float*)d_in[22];
    const float* lin3b = (const float*)d_in[23];
    float* out = (float*)d_out;

    char* p = (char*)d_ws;
    size_t off = 0;
    auto alloc = [&](size_t bytes) -> void* {
        void* r = p + off;
        off = (off + bytes + 255) & ~(size_t)255;
        return r;
    };
    unsigned short* hpre = (unsigned short*)alloc((size_t)N0 * 128 * 2);  // bf16
    float* hpost  = (float*)alloc((size_t)N0 * 128 * 4);
    float* hs     = (float*)alloc((size_t)N0 * 4);
    float* score  = (float*)alloc((size_t)N0 * 4);
    int* deg_out  = (int*)alloc((size_t)N0 * 4);
    int* fill     = (int*)alloc((size_t)N0 * 4);
    unsigned* dp_s = (unsigned*)alloc((size_t)HSLICE * N0 * 4);  // src partials (6.4MB)
    unsigned* dp_d = (unsigned*)alloc((size_t)HSLICE * N0 * 4);  // dst partials/offsets
    int2* epair1  = (int2*)alloc((size_t)NEDGE * 8);   // compacted level-1 edges
    int* csr_src  = (int*)alloc((size_t)N0 * STRIDE * 4);
    int* newid    = (int*)alloc((size_t)N0 * 4);
    int* oldid    = (int*)alloc((size_t)25000 * 4);
    float* garr   = (float*)alloc((size_t)25000 * 4);
    float* maxbuf = (float*)alloc(3 * 128 * 4);
    float* finalv = (float*)alloc(256 * 4);
    float* f1raw  = (float*)alloc(256 * 4);
    float* f2v    = (float*)alloc(128 * 4);
    int* ctrl     = (int*)alloc(64 * 4);
    int* binsA    = (int*)alloc(65536 * 4);
    int* binsB    = (int*)alloc(65536 * 4);
    // epair2 lives only between L2-rmbuild and consumption; hpre is dead then.
    int2* epair2  = (int2*)hpre;

    const int nb[3] = {50000, 25000, 12500};
    const int kb[3] = {25000, 12500, 6250};

    k_init<<<256, 256, 0, stream>>>(finalv, f1raw, binsA, binsB, maxbuf, ctrl);

    for (int b = 0; b < 3; ++b) {
        int n = nb[b], k = kb[b];
        int B = (n + 1023) / 1024;
        if (b == 0) {
            k_hist2<<<HSLICE * 8, 1024, 0, stream>>>(src, dst, dp_s, dp_d);
            k_dsum<<<(N0 + 255) / 256, 256, 0, stream>>>(dp_s, dp_d, deg_out, fill);
            k_fill<<<HSLICE * 8, 1024, 0, stream>>>(src, dst, dp_d, csr_src);
        } else if (b == 1) {
            k_rmbuild<<<(NEDGE + 1023) / 1024, 1024, 0, stream>>>(
                src, dst, (const int2*)0, 0, ctrl, -1, newid, epair1, ctrl + 8,
                deg_out, fill, csr_src);
        } else {
            k_rmbuild<<<(NEDGE + 1023) / 1024, 1024, 0, stream>>>(
                (const int*)0, (const int*)0, epair1, 1, ctrl, 8, newid, epair2, ctrl + 9,
                deg_out, fill, csr_src);
        }
        k_gemm<<<(n + 63) / 64, 256, 0, stream>>>(feat, hpost, oldid, garr, deg_out, cW[b],
                                                  hpre, n, (b > 0) ? nb[b - 1] : 1,
                                                  (b == 0) ? 0 : 1);
        k_agg_conv<<<(n + 3) / 4, 256, 0, stream>>>(hpre, fill, deg_out, csr_src, cb[b],
                                                    sW[b], hpost, hs, n);
        k_score_hist<<<(n + 255) / 256, 256, 0, stream>>>(hs, fill, csr_src, sb[b],
                                                          score, binsA, n);
        k_rpick<<<1, 1024, 0, stream>>>(0, k, ctrl, binsA);
        k_rhist2<<<128, 256, 0, stream>>>(score, ctrl, n, binsB);
        k_rpick<<<1, 1024, 0, stream>>>(1, k, ctrl, binsB);
        k_cemit2<<<B, 1024, 0, stream>>>(score, ctrl, n, (b < 2) ? kb[b] : 0,
                                         newid, oldid, garr, deg_out, fill, binsA, binsB,
                                         hpost, finalv, maxbuf + b * 128,
                                         1.0f / (float)k);
    }

    k_mlp1<<<10, 256, 0, stream>>>(finalv, maxbuf, seq, lin1W, f1raw);
    k_mlp2<<<1, 128, 0, stream>>>(f1raw, lin1b, lin2W, lin2b, f2v);
    k_mlp3<<<16, 128, 0, stream>>>(f2v, lin3W, lin3b, out);
}